// Round 10
// baseline (259.567 us; speedup 1.0000x reference)
//
#include <hip/hip_runtime.h>
#include <hip/hip_bf16.h>
#include <stdint.h>

typedef unsigned short u16;
typedef unsigned int u32;
typedef __attribute__((ext_vector_type(8))) __bf16 bf16x8;
typedef __attribute__((ext_vector_type(8))) u16 u16x8;
typedef __attribute__((ext_vector_type(4))) u16 u16x4;
typedef __attribute__((ext_vector_type(4))) float f32x4;
typedef __attribute__((ext_vector_type(4))) u32 u32x4;

#define S_LEN 2048
#define QSCALE 0.180336880f   /* (1/8) * log2(e) */

__device__ __forceinline__ u16 f2bf(float f) {
  u32 u = __builtin_bit_cast(u32, f);
  u32 r = u + 0x7fffu + ((u >> 16) & 1u);   // round-to-nearest-even
  return (u16)(r >> 16);
}
__device__ __forceinline__ float bf2f(u16 h) {
  u32 u = ((u32)h) << 16;
  return __builtin_bit_cast(float, u);
}
__device__ __forceinline__ float ex2(float x) { return __builtin_exp2f(x); }

__device__ __forceinline__ void gload_lds16(const void* g, void* l) {
  __builtin_amdgcn_global_load_lds(
      (const __attribute__((address_space(1))) void*)g,
      (__attribute__((address_space(3))) void*)l, 16, 0, 0);
}

// ---------------------------------------------------------------------------
// fused fp32 -> bf16 conversion of x | Wqkv | Wout (one launch)
// ---------------------------------------------------------------------------
#define N4_X 1048576
#define N4_WQKV 786432
#define N4_WOUT 262144
__global__ void f2bf_all(const float* __restrict__ x, const float* __restrict__ wq,
                         const float* __restrict__ wo, u16* __restrict__ xb,
                         u16* __restrict__ wqb, u16* __restrict__ wob) {
  int i = blockIdx.x * blockDim.x + threadIdx.x;
  int stride = gridDim.x * blockDim.x;
  const int total = N4_X + N4_WQKV + N4_WOUT;
  for (; i < total; i += stride) {
    const float4* src; ushort4* dst; int k;
    if (i < N4_X) { src = (const float4*)x; dst = (ushort4*)xb; k = i; }
    else if (i < N4_X + N4_WQKV) { src = (const float4*)wq; dst = (ushort4*)wqb; k = i - N4_X; }
    else { src = (const float4*)wo; dst = (ushort4*)wob; k = i - N4_X - N4_WQKV; }
    float4 v = src[k];
    ushort4 o;
    o.x = f2bf(v.x); o.y = f2bf(v.y); o.z = f2bf(v.z); o.w = f2bf(v.w);
    dst[k] = o;
  }
}

// ---------------------------------------------------------------------------
// C = A * B^T + bias.  A:[M,K] bf16, B:[N,K] bf16 (row-major, K contig).
// 128x128 tile, BK=32, 4 waves (2x2). MODE 0: fp32 C0 (ldc).
// MODE 2: QKV split — cols<1024 (Q) -> bf16 C0, scaled by QSCALE;
//         cols in [1024,2048) (K) -> bf16 C0 (ld 2048); cols>=2048 (V) ->
//         transposed bf16 C1 as vt[b*16+h][d][s] (packed 4-row stores).
// ---------------------------------------------------------------------------
template<int MODE>
__global__ __launch_bounds__(256) void gemm_bt(
    const u16* __restrict__ A, const u16* __restrict__ B,
    const float* __restrict__ bias, void* __restrict__ C0,
    u16* __restrict__ C1, int M, int N, int K, int ldc) {
  __shared__ __align__(16) u16 As[128 * 32];
  __shared__ __align__(16) u16 Bs[128 * 32];
  const int tid = threadIdx.x;
  const int wid = tid >> 6, lane = tid & 63;
  const int l15 = lane & 15, l4 = lane >> 4;
  const int wr = wid >> 1, wc = wid & 1;
  const int bm = blockIdx.y * 128, bn = blockIdx.x * 128;

  f32x4 acc[4][4] = {};

  for (int k0 = 0; k0 < K; k0 += 32) {
#pragma unroll
    for (int i = 0; i < 2; ++i) {
      int c = i * 256 + wid * 64 + lane;              // chunk id (16B each)
      int row = c >> 2, kc = c & 3;
      gload_lds16(A + (size_t)(bm + row) * K + k0 + kc * 8,
                  (char*)As + (i * 256 + wid * 64) * 16);
      gload_lds16(B + (size_t)(bn + row) * K + k0 + kc * 8,
                  (char*)Bs + (i * 256 + wid * 64) * 16);
    }
    __syncthreads();

    bf16x8 a[4], b[4];
#pragma unroll
    for (int mi = 0; mi < 4; ++mi)
      a[mi] = __builtin_bit_cast(bf16x8,
          *(const u32x4*)&As[(wr * 64 + mi * 16 + l15) * 32 + l4 * 8]);
#pragma unroll
    for (int ni = 0; ni < 4; ++ni)
      b[ni] = __builtin_bit_cast(bf16x8,
          *(const u32x4*)&Bs[(wc * 64 + ni * 16 + l15) * 32 + l4 * 8]);
#pragma unroll
    for (int mi = 0; mi < 4; ++mi)
#pragma unroll
      for (int ni = 0; ni < 4; ++ni)
        acc[mi][ni] = __builtin_amdgcn_mfma_f32_16x16x32_bf16(
            a[mi], b[ni], acc[mi][ni], 0, 0, 0);
    __syncthreads();
  }

#pragma unroll
  for (int ni = 0; ni < 4; ++ni) {
    int col = bn + wc * 64 + ni * 16 + l15;
    float bv = bias[col];
#pragma unroll
    for (int mi = 0; mi < 4; ++mi) {
      int row = bm + wr * 64 + mi * 16 + l4 * 4;
      if (MODE == 0) {
#pragma unroll
        for (int r = 0; r < 4; ++r)
          ((float*)C0)[(size_t)(row + r) * ldc + col] = acc[mi][ni][r] + bv;
      } else {
        if (col < 2048) {
          float sc = (col < 1024) ? QSCALE : 1.0f;
#pragma unroll
          for (int r = 0; r < 4; ++r)
            ((u16*)C0)[(size_t)(row + r) * 2048 + col] = f2bf((acc[mi][ni][r] + bv) * sc);
        } else {
          u16x4 vv;
#pragma unroll
          for (int r = 0; r < 4; ++r) vv[r] = f2bf(acc[mi][ni][r] + bv);
          int hh = (col - 2048) >> 6, d = (col - 2048) & 63;
          int bb = row >> 11, s = row & 2047;
          *(u16x4*)&C1[(((size_t)(bb * 16 + hh) * 64 + d) << 11) + s] = vv;
        }
      }
    }
  }
}

// ---------------------------------------------------------------------------
// Causal flash attention, split-KV, swapped QK^T, ZERO LDS STAGING:
// K and V^T fragments load directly from global (K/V are L2/L3-resident;
// staging cache-fit data in LDS is pure overhead). No __syncthreads at all —
// the 4 waves run free. Softmax/pack/bpermute/PV identical to round 9.
// ---------------------------------------------------------------------------
__global__ __launch_bounds__(256, 4) void attn7(
    const u16* __restrict__ qk, const u16* __restrict__ vt,
    u16* __restrict__ O, u16* __restrict__ pO, float* __restrict__ ML) {
  const int tid = threadIdx.x;
  const int wid = tid >> 6, lane = tid & 63;
  const int l15 = lane & 15, l4 = lane >> 4;
  const int i = blockIdx.x, bh = blockIdx.y;
  const int b = bh >> 4, h = bh & 15;

  // decode (qt, kt-range, mode); ordered roughly longest-first
  int qt, k0t, mode;
  if (i < 16)      { qt = 16 + i;  k0t = 0;  mode = 0; }   // part0, len 16
  else if (i < 32) { qt = 47 - i;  k0t = 16; mode = 1; }   // part1, len qt-15
  else             { qt = 47 - i;  k0t = 0;  mode = 2; }   // single, len qt+1
  const int k1t = (mode == 0) ? 15 : qt;

  const u16* qkb = qk + (((size_t)b * S_LEN) << 11);
  const u16* vtb = vt + ((size_t)bh << 17);           // 64*2048 per (b,h)
  const int qcol = h * 64, kcol = 1024 + h * 64;

  // Q fragments: B-operand of swapped mfma = Q[q=l15][d=l4*8+j]
  bf16x8 qf[2];
  {
    int rq = qt * 64 + wid * 16 + l15;
#pragma unroll
    for (int kf = 0; kf < 2; ++kf)
      qf[kf] = __builtin_bit_cast(bf16x8,
          *(const u16x8*)&qkb[((size_t)rq << 11) + qcol + kf * 32 + l4 * 8]);
  }

  // per-lane fragment base pointers (advance by kvb per tile)
  //   K frag (A-op): K[kv=kvb+nt*16+l15][d=kf*32+l4*8+j]
  const u16* kfb = qkb + (((size_t)l15) << 11) + kcol + l4 * 8;
  //   V frag (B-op): V^T[d=dt*16+l15][kv=kvb+kf*32+l4*8+j]
  const u16* vfb = vtb + (((size_t)l15) << 11) + l4 * 8;

  const int qpos = qt * 64 + wid * 16 + l15;   // this lane's q-row
  // bpermute source addresses for the P redistribution (bytes = lane*4)
  const int addrA = (l15 + ((lane & 16) << 1)) << 2;
  const int addrB = addrA + 64;
  const bool hiHalf = (l4 >= 2);

  float m_ = -__builtin_inff(), l_ = 0.f;
  f32x4 o_[4] = {};

  for (int kt = k0t; kt <= k1t; ++kt) {
    const int kvb = kt << 6;

    // ---- S^T = K Q^T (log2 domain): s[nt][r] = S[q=l15][kv=nt*16+l4*4+r] --
    const u16* kr = kfb + (((size_t)kvb) << 11);
    f32x4 s[4] = {};
#pragma unroll
    for (int kf = 0; kf < 2; ++kf)
#pragma unroll
      for (int nt = 0; nt < 4; ++nt) {
        bf16x8 kf8 = __builtin_bit_cast(bf16x8,
            *(const u16x8*)(kr + (((size_t)(nt * 16)) << 11) + kf * 32));
        s[nt] = __builtin_amdgcn_mfma_f32_16x16x32_bf16(kf8, qf[kf], s[nt], 0, 0, 0);
      }

    // ---- causal mask (diagonal tile only; kv = kvb+nt*16+l4*4+r) ----
    if (kt == qt) {
#pragma unroll
      for (int nt = 0; nt < 4; ++nt) {
        int kvr = kvb + nt * 16 + l4 * 4;
#pragma unroll
        for (int r = 0; r < 4; ++r)
          if (kvr + r > qpos) s[nt][r] = -__builtin_inff();
      }
    }

    // ---- online softmax: in-register trees + 2 shfl; exact rescale-skip ----
    {
      f32x4 t01 = {fmaxf(s[0][0], s[1][0]), fmaxf(s[0][1], s[1][1]),
                   fmaxf(s[0][2], s[1][2]), fmaxf(s[0][3], s[1][3])};
      f32x4 t23 = {fmaxf(s[2][0], s[3][0]), fmaxf(s[2][1], s[3][1]),
                   fmaxf(s[2][2], s[3][2]), fmaxf(s[2][3], s[3][3])};
      float pm = fmaxf(fmaxf(fmaxf(t01[0], t23[0]), fmaxf(t01[1], t23[1])),
                       fmaxf(fmaxf(t01[2], t23[2]), fmaxf(t01[3], t23[3])));
      pm = fmaxf(pm, __shfl_xor(pm, 16));
      pm = fmaxf(pm, __shfl_xor(pm, 32));
      bool need = pm > m_;
      if (__any((int)need)) {              // exact: skipped only when es==1
        float nm = fmaxf(m_, pm);
        float es = ex2(m_ - nm);
        m_ = nm;
        l_ *= es;
#pragma unroll
        for (int r = 0; r < 4; ++r) {
          float esr = __shfl(es, (l4 << 4) + l4 * 4 + r);
#pragma unroll
          for (int dt = 0; dt < 4; ++dt) o_[dt][r] *= esr;
        }
      }
#pragma unroll
      for (int nt = 0; nt < 4; ++nt)
#pragma unroll
        for (int r = 0; r < 4; ++r)
          s[nt][r] = ex2(s[nt][r] - m_);
      float ts = ((s[0][0] + s[0][1]) + (s[0][2] + s[0][3]))
               + ((s[1][0] + s[1][1]) + (s[1][2] + s[1][3]))
               + ((s[2][0] + s[2][1]) + (s[2][2] + s[2][3]))
               + ((s[3][0] + s[3][1]) + (s[3][2] + s[3][3]));
      l_ += ts;
    }

    // ---- pack P to bf16 pairs: pk[nt][w] = kv {nt*16+l4*4+2w, +1} ----
    u32 pk[4][2];
#pragma unroll
    for (int nt = 0; nt < 4; ++nt) {
      pk[nt][0] = (u32)f2bf(s[nt][0]) | ((u32)f2bf(s[nt][1]) << 16);
      pk[nt][1] = (u32)f2bf(s[nt][2]) | ((u32)f2bf(s[nt][3]) << 16);
    }

    // ---- O += P V: redistribute P via ds_bpermute; V direct from global ----
    const u16* vr = vfb + kvb;
#pragma unroll
    for (int kf = 0; kf < 2; ++kf) {
      u32 w[4];
#pragma unroll
      for (int wi = 0; wi < 4; ++wi) {
        int ad = (wi < 2) ? addrA : addrB;
        u32 lo = __builtin_amdgcn_ds_bpermute(ad, (int)pk[2 * kf][wi & 1]);
        u32 hi = __builtin_amdgcn_ds_bpermute(ad, (int)pk[2 * kf + 1][wi & 1]);
        w[wi] = hiHalf ? hi : lo;
      }
      bf16x8 pa = __builtin_bit_cast(bf16x8, u32x4{w[0], w[1], w[2], w[3]});
#pragma unroll
      for (int dt = 0; dt < 4; ++dt) {
        bf16x8 vf = __builtin_bit_cast(bf16x8,
            *(const u16x8*)(vr + (((size_t)(dt * 16)) << 11) + kf * 32));
        o_[dt] = __builtin_amdgcn_mfma_f32_16x16x32_bf16(pa, vf, o_[dt], 0, 0, 0);
      }
    }
  }

  // ---- epilogue: finish l reduce (across l4), normalize, store ----
  float lt = l_ + __shfl_xor(l_, 16);
  lt += __shfl_xor(lt, 32);
  float linv = 1.0f / lt;
  float li4[4];
#pragma unroll
  for (int r = 0; r < 4; ++r)
    li4[r] = __shfl(linv, (l4 << 4) + l4 * 4 + r);

  if (mode == 2) {
#pragma unroll
    for (int dt = 0; dt < 4; ++dt)
#pragma unroll
      for (int r = 0; r < 4; ++r) {
        float val = o_[dt][r] * li4[r];
        int tok = qt * 64 + wid * 16 + l4 * 4 + r;
        O[(((size_t)(b * S_LEN + tok)) << 10) + h * 64 + dt * 16 + l15] = f2bf(val);
      }
  } else {
    const int pslot = (((bh << 4) + (qt - 16)) << 1) + mode;
    u16* pb = pO + ((size_t)pslot << 12);
#pragma unroll
    for (int dt = 0; dt < 4; ++dt)
#pragma unroll
      for (int r = 0; r < 4; ++r) {
        int row = wid * 16 + l4 * 4 + r;
        pb[row * 64 + dt * 16 + l15] = f2bf(o_[dt][r] * li4[r]);
      }
    if (l4 == 0) {                      // m_/lt live at q = l15, uniform in l4
      ML[pslot * 128 + wid * 16 + l15] = m_;
      ML[pslot * 128 + 64 + wid * 16 + l15] = lt;
    }
  }
}

// ---------------------------------------------------------------------------
// Merge the two partials of each qt>=16 q-tile into O.
// ---------------------------------------------------------------------------
__global__ __launch_bounds__(256) void combine(
    const u16* __restrict__ pO, const float* __restrict__ ML,
    u16* __restrict__ O) {
  const int qi = blockIdx.x, bh = blockIdx.y;
  const int b = bh >> 4, h = bh & 15;
  const int t = threadIdx.x;
  const int row = t >> 2, cblk = (t & 3) << 4;      // 16 cols per thread
  const int s0 = (((bh << 4) + qi) << 1), s1 = s0 + 1;
  float m0 = ML[s0 * 128 + row], l0 = ML[s0 * 128 + 64 + row];
  float m1 = ML[s1 * 128 + row], l1 = ML[s1 * 128 + 64 + row];
  float m = fmaxf(m0, m1);
  float w0 = l0 * ex2(m0 - m), w1 = l1 * ex2(m1 - m);
  float inv = 1.0f / (w0 + w1);
  w0 *= inv; w1 *= inv;
  const u16* p0 = pO + (((size_t)s0) << 12) + row * 64 + cblk;
  const u16* p1 = pO + (((size_t)s1) << 12) + row * 64 + cblk;
  const int tok = (16 + qi) * 64 + row;
  u16* dst = O + (((size_t)(b * S_LEN + tok)) << 10) + h * 64 + cblk;
#pragma unroll
  for (int half = 0; half < 2; ++half) {
    u16x8 a = *(const u16x8*)(p0 + half * 8);
    u16x8 c = *(const u16x8*)(p1 + half * 8);
    u16x8 o;
#pragma unroll
    for (int j = 0; j < 8; ++j)
      o[j] = f2bf(w0 * bf2f(a[j]) + w1 * bf2f(c[j]));
    *(u16x8*)(dst + half * 8) = o;
  }
}

// ---------------------------------------------------------------------------
extern "C" void kernel_launch(void* const* d_in, const int* in_sizes, int n_in,
                              void* d_out, int out_size, void* d_ws, size_t ws_size,
                              hipStream_t stream) {
  const float* x    = (const float*)d_in[0];
  const float* Wqkv = (const float*)d_in[1];
  const float* bqkv = (const float*)d_in[2];
  const float* Wout = (const float*)d_in[3];
  const float* bout = (const float*)d_in[4];
  float* out = (float*)d_out;

  // workspace layout (u16 elems): ~51 MiB total
  u16* xb    = (u16*)d_ws;            // 4,194,304   (dead after QKV GEMM)
  u16* wqkvb = xb + 4194304;          // 3,145,728   (dead after QKV GEMM)
  u16* woutb = wqkvb + 3145728;       // 1,048,576
  u16* qkb   = woutb + 1048576;       // 8,388,608  (Q|K, [4096][2048])
  u16* vtb   = qkb + 8388608;         // 4,194,304  (V^T, [32][64][2048])
  u16* ob    = vtb + 4194304;         // 4,194,304
  // attention partials alias the dead xb/wqkvb regions:
  u16*   pO = xb;                     // 1024 slots x 64x64 bf16 = 4,194,304 u16
  float* ML = (float*)wqkvb;          // 1024 slots x 128 f32    = 131,072 f32

  f2bf_all<<<2048, 256, 0, stream>>>(x, Wqkv, Wout, xb, wqkvb, woutb);

  gemm_bt<2><<<dim3(24, 32), 256, 0, stream>>>(xb, wqkvb, bqkv, qkb, vtb,
                                               4096, 3072, 1024, 0);
  attn7<<<dim3(48, 32), 256, 0, stream>>>(qkb, vtb, ob, pO, ML);
  combine<<<dim3(16, 32), 256, 0, stream>>>(pO, ML, ob);
  gemm_bt<0><<<dim3(8, 32), 256, 0, stream>>>(ob, woutb, bout, out, nullptr,
                                              4096, 1024, 1024, 1024);
}

// Round 11
// 172.032 us; speedup vs baseline: 1.5088x; 1.5088x over previous
//
#include <hip/hip_runtime.h>
#include <hip/hip_bf16.h>
#include <stdint.h>

typedef unsigned short u16;
typedef unsigned int u32;
typedef __attribute__((ext_vector_type(8))) __bf16 bf16x8;
typedef __attribute__((ext_vector_type(8))) u16 u16x8;
typedef __attribute__((ext_vector_type(4))) u16 u16x4;
typedef __attribute__((ext_vector_type(4))) float f32x4;
typedef __attribute__((ext_vector_type(4))) u32 u32x4;

#define S_LEN 2048
#define QSCALE 0.180336880f   /* (1/8) * log2(e) */

__device__ __forceinline__ u16 f2bf(float f) {
  u32 u = __builtin_bit_cast(u32, f);
  u32 r = u + 0x7fffu + ((u >> 16) & 1u);   // round-to-nearest-even
  return (u16)(r >> 16);
}
__device__ __forceinline__ float bf2f(u16 h) {
  u32 u = ((u32)h) << 16;
  return __builtin_bit_cast(float, u);
}
__device__ __forceinline__ float ex2(float x) { return __builtin_exp2f(x); }

__device__ __forceinline__ void gload_lds16(const void* g, void* l) {
  __builtin_amdgcn_global_load_lds(
      (const __attribute__((address_space(1))) void*)g,
      (__attribute__((address_space(3))) void*)l, 16, 0, 0);
}

// ---------------------------------------------------------------------------
// fused fp32 -> bf16 conversion of x | Wqkv | Wout (one launch)
// ---------------------------------------------------------------------------
#define N4_X 1048576
#define N4_WQKV 786432
#define N4_WOUT 262144
__global__ void f2bf_all(const float* __restrict__ x, const float* __restrict__ wq,
                         const float* __restrict__ wo, u16* __restrict__ xb,
                         u16* __restrict__ wqb, u16* __restrict__ wob) {
  int i = blockIdx.x * blockDim.x + threadIdx.x;
  int stride = gridDim.x * blockDim.x;
  const int total = N4_X + N4_WQKV + N4_WOUT;
  for (; i < total; i += stride) {
    const float4* src; ushort4* dst; int k;
    if (i < N4_X) { src = (const float4*)x; dst = (ushort4*)xb; k = i; }
    else if (i < N4_X + N4_WQKV) { src = (const float4*)wq; dst = (ushort4*)wqb; k = i - N4_X; }
    else { src = (const float4*)wo; dst = (ushort4*)wob; k = i - N4_X - N4_WQKV; }
    float4 v = src[k];
    ushort4 o;
    o.x = f2bf(v.x); o.y = f2bf(v.y); o.z = f2bf(v.z); o.w = f2bf(v.w);
    dst[k] = o;
  }
}

// ---------------------------------------------------------------------------
// C = A * B^T + bias.  A:[M,K] bf16, B:[N,K] bf16 (row-major, K contig).
// 128x128 tile, BK=32, 4 waves (2x2). MODE 0: fp32 C0 (ldc).
// MODE 2: QKV split — cols<1024 (Q) -> bf16 C0, scaled by QSCALE;
//         cols in [1024,2048) (K) -> bf16 C0 (ld 2048); cols>=2048 (V) ->
//         transposed bf16 C1 as vt[b*16+h][d][s] (packed 4-row stores).
// ---------------------------------------------------------------------------
template<int MODE>
__global__ __launch_bounds__(256) void gemm_bt(
    const u16* __restrict__ A, const u16* __restrict__ B,
    const float* __restrict__ bias, void* __restrict__ C0,
    u16* __restrict__ C1, int M, int N, int K, int ldc) {
  __shared__ __align__(16) u16 As[128 * 32];
  __shared__ __align__(16) u16 Bs[128 * 32];
  const int tid = threadIdx.x;
  const int wid = tid >> 6, lane = tid & 63;
  const int l15 = lane & 15, l4 = lane >> 4;
  const int wr = wid >> 1, wc = wid & 1;
  const int bm = blockIdx.y * 128, bn = blockIdx.x * 128;

  f32x4 acc[4][4] = {};

  for (int k0 = 0; k0 < K; k0 += 32) {
#pragma unroll
    for (int i = 0; i < 2; ++i) {
      int c = i * 256 + wid * 64 + lane;              // chunk id (16B each)
      int row = c >> 2, kc = c & 3;
      gload_lds16(A + (size_t)(bm + row) * K + k0 + kc * 8,
                  (char*)As + (i * 256 + wid * 64) * 16);
      gload_lds16(B + (size_t)(bn + row) * K + k0 + kc * 8,
                  (char*)Bs + (i * 256 + wid * 64) * 16);
    }
    __syncthreads();

    bf16x8 a[4], b[4];
#pragma unroll
    for (int mi = 0; mi < 4; ++mi)
      a[mi] = __builtin_bit_cast(bf16x8,
          *(const u32x4*)&As[(wr * 64 + mi * 16 + l15) * 32 + l4 * 8]);
#pragma unroll
    for (int ni = 0; ni < 4; ++ni)
      b[ni] = __builtin_bit_cast(bf16x8,
          *(const u32x4*)&Bs[(wc * 64 + ni * 16 + l15) * 32 + l4 * 8]);
#pragma unroll
    for (int mi = 0; mi < 4; ++mi)
#pragma unroll
      for (int ni = 0; ni < 4; ++ni)
        acc[mi][ni] = __builtin_amdgcn_mfma_f32_16x16x32_bf16(
            a[mi], b[ni], acc[mi][ni], 0, 0, 0);
    __syncthreads();
  }

#pragma unroll
  for (int ni = 0; ni < 4; ++ni) {
    int col = bn + wc * 64 + ni * 16 + l15;
    float bv = bias[col];
#pragma unroll
    for (int mi = 0; mi < 4; ++mi) {
      int row = bm + wr * 64 + mi * 16 + l4 * 4;
      if (MODE == 0) {
#pragma unroll
        for (int r = 0; r < 4; ++r)
          ((float*)C0)[(size_t)(row + r) * ldc + col] = acc[mi][ni][r] + bv;
      } else {
        if (col < 2048) {
          float sc = (col < 1024) ? QSCALE : 1.0f;
#pragma unroll
          for (int r = 0; r < 4; ++r)
            ((u16*)C0)[(size_t)(row + r) * 2048 + col] = f2bf((acc[mi][ni][r] + bv) * sc);
        } else {
          u16x4 vv;
#pragma unroll
          for (int r = 0; r < 4; ++r) vv[r] = f2bf(acc[mi][ni][r] + bv);
          int hh = (col - 2048) >> 6, d = (col - 2048) & 63;
          int bb = row >> 11, s = row & 2047;
          *(u16x4*)&C1[(((size_t)(bb * 16 + hh) * 64 + d) << 11) + s] = vv;
        }
      }
    }
  }
}

// ---------------------------------------------------------------------------
// Causal flash attention, WAVE-AUTONOMOUS: each wave owns a 16-row q-tile and
// a KV partition (cap 24 tiles of KVBLK=32), stages K/V into its PRIVATE 8KB
// LDS slice via global_load_lds, and syncs only on its own vmcnt. No
// __syncthreads anywhere. Swapped QK^T in-register softmax (r9-proven).
// Work items per bh = 240: qs>=96 -> 3 parts, 48..95 -> 2, <48 -> single.
// ---------------------------------------------------------------------------
__global__ __launch_bounds__(256, 5) void attn8(
    const u16* __restrict__ qk, const u16* __restrict__ vt,
    u16* __restrict__ O, u16* __restrict__ pO, float* __restrict__ ML) {
  __shared__ __align__(16) u16 KS[4][32 * 64];
  __shared__ __align__(16) u16 VS[4][64 * 32];
  const int tid = threadIdx.x;
  const int wid = tid >> 6, lane = tid & 63;
  const int l15 = lane & 15, l4 = lane >> 4;
  const int bh = blockIdx.y;
  const int b = bh >> 4, h = bh & 15;

  // ---- work-item decode: item -> (qs, part) ----
  const int item = blockIdx.x * 4 + wid;       // 0..239
  int qs, p;
  if (item < 96)       { qs = 96 + item / 3; p = item % 3; }       // 3-part
  else if (item < 192) { int u = item - 96; qs = 48 + u / 2; p = u & 1; } // 2-part
  else                 { qs = 47 - (item - 192); p = 0; }          // singles
  const int nts = (qs >> 1) + 1;               // kv tiles (32 each) before diag
  const int kt0 = p * 24;
  const int kt1 = min(kt0 + 23, nts - 1);

  const u16* qkb = qk + (((size_t)b * S_LEN) << 11);
  const u16* vtb = vt + ((size_t)bh << 17);
  const int qcol = h * 64, kcol = 1024 + h * 64;

  u16* Kw = &KS[wid][0];
  u16* Vw = &VS[wid][0];

  // Q fragments (B-op): Q[q=qs*16+l15][d=kf*32+l4*8+j], log2-pre-scaled
  bf16x8 qf[2];
  {
    int rq = qs * 16 + l15;
#pragma unroll
    for (int kf = 0; kf < 2; ++kf)
      qf[kf] = __builtin_bit_cast(bf16x8,
          *(const u16x8*)&qkb[((size_t)rq << 11) + qcol + kf * 32 + l4 * 8]);
  }
  const int qpos = qs * 16 + l15;

  // bpermute addresses (r7-verified mapping, kf = 0 only at KVBLK=32)
  const int addrA = (l15 + ((lane & 16) << 1)) << 2;
  const int addrB = addrA + 64;
  const bool hiHalf = (l4 >= 2);

  float m_ = -__builtin_inff(), l_ = 0.f;
  f32x4 o_[4] = {};

  for (int kt = kt0; kt <= kt1; ++kt) {
    const int kvb = kt << 5;

    // ---- stage K tile [32][64] then V tile [64][32] (pre-swizzled src) ----
#pragma unroll
    for (int ci = 0; ci < 4; ++ci) {
      int c = ci * 64 + lane;
      int row = c >> 3, dch = c & 7;
      int slot = dch ^ (row & 7);
      gload_lds16(qkb + (((size_t)(kvb + row)) << 11) + kcol + slot * 8,
                  (char*)Kw + c * 16);
    }
#pragma unroll
    for (int ci = 0; ci < 4; ++ci) {
      int c = ci * 64 + lane;
      int row = c >> 2, kch = c & 3;
      int slot = kch ^ (row & 3) ^ ((row >> 2) & 3);
      gload_lds16(vtb + (((size_t)row) << 11) + kvb + slot * 8,
                  (char*)Vw + c * 16);
    }
    asm volatile("s_waitcnt vmcnt(4)" ::: "memory");   // K landed; V in flight

    // ---- S^T = K Q^T: s[nt][r] = S[q=l15][kv=nt*16+l4*4+r] ----
    f32x4 s[2] = {};
#pragma unroll
    for (int kf = 0; kf < 2; ++kf)
#pragma unroll
      for (int nt = 0; nt < 2; ++nt) {
        int row = nt * 16 + l15;
        int slot = (kf * 4 + l4) ^ (row & 7);
        bf16x8 kf8 = __builtin_bit_cast(bf16x8,
            *(const u32x4*)((const char*)Kw + row * 128 + slot * 16));
        s[nt] = __builtin_amdgcn_mfma_f32_16x16x32_bf16(kf8, qf[kf], s[nt], 0, 0, 0);
      }

    // ---- causal mask (diag tile only) ----
    if (kt == nts - 1) {
#pragma unroll
      for (int nt = 0; nt < 2; ++nt) {
        int kvr = kvb + nt * 16 + l4 * 4;
#pragma unroll
        for (int r = 0; r < 4; ++r)
          if (kvr + r > qpos) s[nt][r] = -__builtin_inff();
      }
    }

    // ---- online softmax (full-row reduce, exact rescale-skip) ----
    {
      float pm = fmaxf(fmaxf(fmaxf(s[0][0], s[0][1]), fmaxf(s[0][2], s[0][3])),
                       fmaxf(fmaxf(s[1][0], s[1][1]), fmaxf(s[1][2], s[1][3])));
      pm = fmaxf(pm, __shfl_xor(pm, 16));
      pm = fmaxf(pm, __shfl_xor(pm, 32));
      bool need = pm > m_;
      if (__any((int)need)) {
        float nm = fmaxf(m_, pm);
        float es = ex2(m_ - nm);
        m_ = nm;
        l_ *= es;
#pragma unroll
        for (int r = 0; r < 4; ++r) {
          float esr = __shfl(es, (l4 << 4) + l4 * 4 + r);
#pragma unroll
          for (int dt = 0; dt < 4; ++dt) o_[dt][r] *= esr;
        }
      }
#pragma unroll
      for (int nt = 0; nt < 2; ++nt)
#pragma unroll
        for (int r = 0; r < 4; ++r)
          s[nt][r] = ex2(s[nt][r] - m_);
      l_ += ((s[0][0] + s[0][1]) + (s[0][2] + s[0][3]))
          + ((s[1][0] + s[1][1]) + (s[1][2] + s[1][3]));
    }

    // ---- pack + bpermute P to A-fragment ----
    u32 pk[2][2];
#pragma unroll
    for (int nt = 0; nt < 2; ++nt) {
      pk[nt][0] = (u32)f2bf(s[nt][0]) | ((u32)f2bf(s[nt][1]) << 16);
      pk[nt][1] = (u32)f2bf(s[nt][2]) | ((u32)f2bf(s[nt][3]) << 16);
    }
    u32 w[4];
#pragma unroll
    for (int wi = 0; wi < 4; ++wi) {
      int ad = (wi < 2) ? addrA : addrB;
      u32 lo = __builtin_amdgcn_ds_bpermute(ad, (int)pk[0][wi & 1]);
      u32 hi = __builtin_amdgcn_ds_bpermute(ad, (int)pk[1][wi & 1]);
      w[wi] = hiHalf ? hi : lo;
    }
    bf16x8 pa = __builtin_bit_cast(bf16x8, u32x4{w[0], w[1], w[2], w[3]});

    asm volatile("s_waitcnt vmcnt(0)" ::: "memory");   // V landed

    // ---- O += P V ----
#pragma unroll
    for (int dt = 0; dt < 4; ++dt) {
      int row = dt * 16 + l15;
      int slot = l4 ^ (row & 3) ^ ((row >> 2) & 3);
      bf16x8 vf = __builtin_bit_cast(bf16x8,
          *(const u32x4*)((const char*)Vw + row * 64 + slot * 16));
      o_[dt] = __builtin_amdgcn_mfma_f32_16x16x32_bf16(pa, vf, o_[dt], 0, 0, 0);
    }
  }

  // ---- epilogue ----
  float lt = l_ + __shfl_xor(l_, 16);
  lt += __shfl_xor(lt, 32);
  float linv = 1.0f / lt;
  float li4[4];
#pragma unroll
  for (int r = 0; r < 4; ++r)
    li4[r] = __shfl(linv, (l4 << 4) + l4 * 4 + r);

  if (qs < 48) {                 // single part: direct write
#pragma unroll
    for (int dt = 0; dt < 4; ++dt)
#pragma unroll
      for (int r = 0; r < 4; ++r) {
        int tok = qs * 16 + l4 * 4 + r;
        O[(((size_t)(b * S_LEN + tok)) << 10) + h * 64 + dt * 16 + l15] =
            f2bf(o_[dt][r] * li4[r]);
      }
  } else {                       // normalized partial + (m,l)
    int sid = (qs < 96) ? (qs - 48) * 2 + p : 96 + (qs - 96) * 3 + p;
    int pslot = bh * 192 + sid;
    u16* pb = pO + ((size_t)pslot << 10);            // 16x64 u16 per slot
#pragma unroll
    for (int dt = 0; dt < 4; ++dt)
#pragma unroll
      for (int r = 0; r < 4; ++r)
        pb[(l4 * 4 + r) * 64 + dt * 16 + l15] = f2bf(o_[dt][r] * li4[r]);
    if (l4 == 0) {               // m_/lt live at q=l15, uniform in l4
      ML[pslot * 32 + l15] = m_;
      ML[pslot * 32 + 16 + l15] = lt;
    }
  }
}

// ---------------------------------------------------------------------------
// Merge the 2-3 partials of each qs>=48 q-tile (16 rows) into O.
// ---------------------------------------------------------------------------
__global__ __launch_bounds__(256) void combine2(
    const u16* __restrict__ pO, const float* __restrict__ ML,
    u16* __restrict__ O) {
  const int qs = 48 + blockIdx.x, bh = blockIdx.y;
  const int b = bh >> 4, h = bh & 15;
  const int nparts = (qs < 96) ? 2 : 3;
  const int sid0 = (qs < 96) ? (qs - 48) * 2 : 96 + (qs - 96) * 3;
  const int t = threadIdx.x;
  const int row = t >> 4, col = (t & 15) << 2;     // 4 cols per thread
  const int base = bh * 192 + sid0;

  float m = -__builtin_inff();
  float mi[3], li[3];
#pragma unroll
  for (int i = 0; i < 3; ++i)
    if (i < nparts) {
      mi[i] = ML[(base + i) * 32 + row];
      li[i] = ML[(base + i) * 32 + 16 + row];
      m = fmaxf(m, mi[i]);
    }
  float wsum = 0.f, wv[3];
#pragma unroll
  for (int i = 0; i < 3; ++i)
    if (i < nparts) { wv[i] = li[i] * ex2(mi[i] - m); wsum += wv[i]; }
  float inv = 1.0f / wsum;

  float acc[4] = {0.f, 0.f, 0.f, 0.f};
#pragma unroll
  for (int i = 0; i < 3; ++i)
    if (i < nparts) {
      u16x4 v = *(const u16x4*)&pO[(((size_t)(base + i)) << 10) + row * 64 + col];
      float wn = wv[i] * inv;
#pragma unroll
      for (int jx = 0; jx < 4; ++jx) acc[jx] += wn * bf2f(v[jx]);
    }
  u16x4 o;
#pragma unroll
  for (int jx = 0; jx < 4; ++jx) o[jx] = f2bf(acc[jx]);
  *(u16x4*)&O[(((size_t)(b * S_LEN + qs * 16 + row)) << 10) + h * 64 + col] = o;
}

// ---------------------------------------------------------------------------
extern "C" void kernel_launch(void* const* d_in, const int* in_sizes, int n_in,
                              void* d_out, int out_size, void* d_ws, size_t ws_size,
                              hipStream_t stream) {
  const float* x    = (const float*)d_in[0];
  const float* Wqkv = (const float*)d_in[1];
  const float* bqkv = (const float*)d_in[2];
  const float* Wout = (const float*)d_in[3];
  const float* bout = (const float*)d_in[4];
  float* out = (float*)d_out;

  // workspace layout (u16 elems): ~51 MiB total
  u16* xb    = (u16*)d_ws;            // 4,194,304   (dead after QKV GEMM)
  u16* wqkvb = xb + 4194304;          // 3,145,728   (dead after QKV GEMM)
  u16* woutb = wqkvb + 3145728;       // 1,048,576
  u16* qkb   = woutb + 1048576;       // 8,388,608  (Q|K, [4096][2048])
  u16* vtb   = qkb + 8388608;         // 4,194,304  (V^T, [32][64][2048])
  u16* ob    = vtb + 4194304;         // 4,194,304
  // attention partials alias the dead xb/wqkvb regions:
  //   pO: 192 slots/bh x 32 bh x 1024 u16 = 6,291,456 u16 (xb + 2M of wqkvb)
  //   ML: 6144 slots x 32 f32 = 196,608 f32 (fits in wqkvb tail)
  u16*   pO = xb;
  float* ML = (float*)(wqkvb + 2097152);

  f2bf_all<<<2048, 256, 0, stream>>>(x, Wqkv, Wout, xb, wqkvb, woutb);

  gemm_bt<2><<<dim3(24, 32), 256, 0, stream>>>(xb, wqkvb, bqkv, qkb, vtb,
                                               4096, 3072, 1024, 0);
  attn8<<<dim3(60, 32), 256, 0, stream>>>(qkb, vtb, ob, pO, ML);
  combine2<<<dim3(80, 32), 256, 0, stream>>>(pO, ML, ob);
  gemm_bt<0><<<dim3(8, 32), 256, 0, stream>>>(ob, woutb, bout, out, nullptr,
                                              4096, 1024, 1024, 1024);
}

// Round 12
// 159.107 us; speedup vs baseline: 1.6314x; 1.0812x over previous
//
#include <hip/hip_runtime.h>
#include <hip/hip_bf16.h>
#include <stdint.h>

typedef unsigned short u16;
typedef unsigned int u32;
typedef __attribute__((ext_vector_type(8))) __bf16 bf16x8;
typedef __attribute__((ext_vector_type(8))) u16 u16x8;
typedef __attribute__((ext_vector_type(4))) u16 u16x4;
typedef __attribute__((ext_vector_type(4))) float f32x4;
typedef __attribute__((ext_vector_type(4))) u32 u32x4;

#define S_LEN 2048
#define QSCALE 0.180336880f   /* (1/8) * log2(e) */

__device__ __forceinline__ u16 f2bf(float f) {
  u32 u = __builtin_bit_cast(u32, f);
  u32 r = u + 0x7fffu + ((u >> 16) & 1u);   // round-to-nearest-even
  return (u16)(r >> 16);
}
__device__ __forceinline__ float bf2f(u16 h) {
  u32 u = ((u32)h) << 16;
  return __builtin_bit_cast(float, u);
}
__device__ __forceinline__ float ex2(float x) { return __builtin_exp2f(x); }

__device__ __forceinline__ void gload_lds16(const void* g, void* l) {
  __builtin_amdgcn_global_load_lds(
      (const __attribute__((address_space(1))) void*)g,
      (__attribute__((address_space(3))) void*)l, 16, 0, 0);
}

// ---------------------------------------------------------------------------
// fused fp32 -> bf16 conversion of x | Wqkv | Wout (one launch)
// ---------------------------------------------------------------------------
#define N4_X 1048576
#define N4_WQKV 786432
#define N4_WOUT 262144
__global__ void f2bf_all(const float* __restrict__ x, const float* __restrict__ wq,
                         const float* __restrict__ wo, u16* __restrict__ xb,
                         u16* __restrict__ wqb, u16* __restrict__ wob) {
  int i = blockIdx.x * blockDim.x + threadIdx.x;
  int stride = gridDim.x * blockDim.x;
  const int total = N4_X + N4_WQKV + N4_WOUT;
  for (; i < total; i += stride) {
    const float4* src; ushort4* dst; int k;
    if (i < N4_X) { src = (const float4*)x; dst = (ushort4*)xb; k = i; }
    else if (i < N4_X + N4_WQKV) { src = (const float4*)wq; dst = (ushort4*)wqb; k = i - N4_X; }
    else { src = (const float4*)wo; dst = (ushort4*)wob; k = i - N4_X - N4_WQKV; }
    float4 v = src[k];
    ushort4 o;
    o.x = f2bf(v.x); o.y = f2bf(v.y); o.z = f2bf(v.z); o.w = f2bf(v.w);
    dst[k] = o;
  }
}

// ---------------------------------------------------------------------------
// C = A * B^T + bias.  A:[M,K] bf16, B:[N,K] bf16 (row-major, K contig).
// 128x128 tile, BK=32, 4 waves (2x2). MODE 0: fp32 C0 (ldc).
// MODE 2: QKV split — cols<1024 (Q) -> bf16 C0, scaled by QSCALE;
//         cols in [1024,2048) (K) -> bf16 C0 (ld 2048); cols>=2048 (V) ->
//         transposed bf16 C1 as vt[b*16+h][d][s] (packed 4-row stores).
// ---------------------------------------------------------------------------
template<int MODE>
__global__ __launch_bounds__(256) void gemm_bt(
    const u16* __restrict__ A, const u16* __restrict__ B,
    const float* __restrict__ bias, void* __restrict__ C0,
    u16* __restrict__ C1, int M, int N, int K, int ldc) {
  __shared__ __align__(16) u16 As[128 * 32];
  __shared__ __align__(16) u16 Bs[128 * 32];
  const int tid = threadIdx.x;
  const int wid = tid >> 6, lane = tid & 63;
  const int l15 = lane & 15, l4 = lane >> 4;
  const int wr = wid >> 1, wc = wid & 1;
  const int bm = blockIdx.y * 128, bn = blockIdx.x * 128;

  f32x4 acc[4][4] = {};

  for (int k0 = 0; k0 < K; k0 += 32) {
#pragma unroll
    for (int i = 0; i < 2; ++i) {
      int c = i * 256 + wid * 64 + lane;              // chunk id (16B each)
      int row = c >> 2, kc = c & 3;
      gload_lds16(A + (size_t)(bm + row) * K + k0 + kc * 8,
                  (char*)As + (i * 256 + wid * 64) * 16);
      gload_lds16(B + (size_t)(bn + row) * K + k0 + kc * 8,
                  (char*)Bs + (i * 256 + wid * 64) * 16);
    }
    __syncthreads();

    bf16x8 a[4], b[4];
#pragma unroll
    for (int mi = 0; mi < 4; ++mi)
      a[mi] = __builtin_bit_cast(bf16x8,
          *(const u32x4*)&As[(wr * 64 + mi * 16 + l15) * 32 + l4 * 8]);
#pragma unroll
    for (int ni = 0; ni < 4; ++ni)
      b[ni] = __builtin_bit_cast(bf16x8,
          *(const u32x4*)&Bs[(wc * 64 + ni * 16 + l15) * 32 + l4 * 8]);
#pragma unroll
    for (int mi = 0; mi < 4; ++mi)
#pragma unroll
      for (int ni = 0; ni < 4; ++ni)
        acc[mi][ni] = __builtin_amdgcn_mfma_f32_16x16x32_bf16(
            a[mi], b[ni], acc[mi][ni], 0, 0, 0);
    __syncthreads();
  }

#pragma unroll
  for (int ni = 0; ni < 4; ++ni) {
    int col = bn + wc * 64 + ni * 16 + l15;
    float bv = bias[col];
#pragma unroll
    for (int mi = 0; mi < 4; ++mi) {
      int row = bm + wr * 64 + mi * 16 + l4 * 4;
      if (MODE == 0) {
#pragma unroll
        for (int r = 0; r < 4; ++r)
          ((float*)C0)[(size_t)(row + r) * ldc + col] = acc[mi][ni][r] + bv;
      } else {
        if (col < 2048) {
          float sc = (col < 1024) ? QSCALE : 1.0f;
#pragma unroll
          for (int r = 0; r < 4; ++r)
            ((u16*)C0)[(size_t)(row + r) * 2048 + col] = f2bf((acc[mi][ni][r] + bv) * sc);
        } else {
          u16x4 vv;
#pragma unroll
          for (int r = 0; r < 4; ++r) vv[r] = f2bf(acc[mi][ni][r] + bv);
          int hh = (col - 2048) >> 6, d = (col - 2048) & 63;
          int bb = row >> 11, s = row & 2047;
          *(u16x4*)&C1[(((size_t)(bb * 16 + hh) * 64 + d) << 11) + s] = vv;
        }
      }
    }
  }
}

// ---------------------------------------------------------------------------
// Causal flash attention, split-KV, swapped QK^T (r9 skeleton) with
// KVBLK=128 per barrier-iteration: each iteration stages a PAIR of 64-kv
// tiles (double-buffered pairs, 64KB LDS) and runs ONE joint softmax over
// 128 kv. Odd tile counts round up; overhang kv are killed by the causal
// mask (kv > qpos), max tile index 31 -> no OOB. s_setprio around MFMA.
// ---------------------------------------------------------------------------
__global__ __launch_bounds__(256, 2) void attn9(
    const u16* __restrict__ qk, const u16* __restrict__ vt,
    u16* __restrict__ O, u16* __restrict__ pO, float* __restrict__ ML) {
  __shared__ __align__(16) u16 Ks[2][2][64 * 64];    // [buf][tile]
  __shared__ __align__(16) u16 Vs[2][2][64 * 64];
  const int tid = threadIdx.x;
  const int wid = tid >> 6, lane = tid & 63;
  const int l15 = lane & 15, l4 = lane >> 4;
  const int i = blockIdx.x, bh = blockIdx.y;
  const int b = bh >> 4, h = bh & 15;

  // decode (qt, kt-range, mode); ordered roughly longest-first
  int qt, k0t, mode;
  if (i < 16)      { qt = 16 + i;  k0t = 0;  mode = 0; }   // part0, tiles 0..15
  else if (i < 32) { qt = 47 - i;  k0t = 16; mode = 1; }   // part1, tiles 16..qt
  else             { qt = 47 - i;  k0t = 0;  mode = 2; }   // single, tiles 0..qt
  const int k1t = (mode == 0) ? 15 : qt;
  const int npairs = (k1t - k0t + 2) >> 1;
  const bool mayMask = (mode != 0);

  const u16* qkb = qk + (((size_t)b * S_LEN) << 11);
  const u16* vtb = vt + ((size_t)bh << 17);           // 64*2048 per (b,h)
  const int qcol = h * 64, kcol = 1024 + h * 64;

  // staging chunk descriptors: chunk c -> row r = c>>3, swizzled col
  const int c0 = tid, c1 = 256 + tid;
  const int r0 = c0 >> 3, sw0 = ((c0 & 7) ^ (r0 & 7)) << 3;
  const int r1 = c1 >> 3, sw1 = ((c1 & 7) ^ (r1 & 7)) << 3;

  auto stageTile = [&](u16* Kd, u16* Vd, int kt) {
    int kvb = kt << 6;
    gload_lds16(qkb + (((size_t)(kvb + r0)) << 11) + kcol + sw0, (char*)Kd + c0 * 16);
    gload_lds16(qkb + (((size_t)(kvb + r1)) << 11) + kcol + sw1, (char*)Kd + c1 * 16);
    gload_lds16(vtb + ((size_t)r0 << 11) + kvb + sw0, (char*)Vd + c0 * 16);
    gload_lds16(vtb + ((size_t)r1 << 11) + kvb + sw1, (char*)Vd + c1 * 16);
  };
  auto stagePair = [&](int bb, int ktp) {
    stageTile(&Ks[bb][0][0], &Vs[bb][0][0], ktp);
    stageTile(&Ks[bb][1][0], &Vs[bb][1][0], ktp + 1);
  };

  // Q fragments: B-operand of swapped mfma = Q[q=l15][d=l4*8+j]
  bf16x8 qf[2];
  {
    int rq = qt * 64 + wid * 16 + l15;
#pragma unroll
    for (int kf = 0; kf < 2; ++kf)
      qf[kf] = __builtin_bit_cast(bf16x8,
          *(const u16x8*)&qkb[((size_t)rq << 11) + qcol + kf * 32 + l4 * 8]);
  }

  const int qpos = qt * 64 + wid * 16 + l15;   // this lane's q-row
  // bpermute source addresses for the P redistribution (bytes = lane*4)
  const int addrA = (l15 + ((lane & 16) << 1)) << 2;
  const int addrB = addrA + 64;
  const bool hiHalf = (l4 >= 2);

  float m_ = -__builtin_inff(), l_ = 0.f;
  f32x4 o_[4] = {};

  stagePair(0, k0t);
  for (int p2 = 0; p2 < npairs; ++p2) {
    const int ktp = k0t + 2 * p2;
    const int kvb = ktp << 6;
    const int bb = p2 & 1;
    __syncthreads();                            // drains stage(bb); guards reuse
    if (p2 + 1 < npairs) stagePair(bb ^ 1, ktp + 2);   // prefetch next pair

    const char* KcA = (const char*)&Ks[bb][0][0];
    const char* KcB = (const char*)&Ks[bb][1][0];
    const char* VcA = (const char*)&Vs[bb][0][0];
    const char* VcB = (const char*)&Vs[bb][1][0];

    // ---- S^T = K Q^T over 128 kv: sA = kv 0..63, sB = kv 64..127 ----
    f32x4 sA[4] = {}, sB[4] = {};
    __builtin_amdgcn_s_setprio(1);
#pragma unroll
    for (int kf = 0; kf < 2; ++kf)
#pragma unroll
      for (int nt = 0; nt < 4; ++nt) {
        int krow = nt * 16 + l15;
        int slot = ((kf * 4 + l4) ^ (krow & 7)) << 4;
        bf16x8 ka = __builtin_bit_cast(bf16x8,
            *(const u32x4*)(KcA + krow * 128 + slot));
        bf16x8 kb = __builtin_bit_cast(bf16x8,
            *(const u32x4*)(KcB + krow * 128 + slot));
        sA[nt] = __builtin_amdgcn_mfma_f32_16x16x32_bf16(ka, qf[kf], sA[nt], 0, 0, 0);
        sB[nt] = __builtin_amdgcn_mfma_f32_16x16x32_bf16(kb, qf[kf], sB[nt], 0, 0, 0);
      }
    __builtin_amdgcn_s_setprio(0);

    // ---- causal mask (last pair of modes 1/2 only; covers overhang) ----
    if (mayMask && p2 == npairs - 1) {
#pragma unroll
      for (int nt = 0; nt < 4; ++nt) {
        int kvrA = kvb + nt * 16 + l4 * 4;
#pragma unroll
        for (int r = 0; r < 4; ++r) {
          if (kvrA + r > qpos)      sA[nt][r] = -__builtin_inff();
          if (kvrA + 64 + r > qpos) sB[nt][r] = -__builtin_inff();
        }
      }
    }

    // ---- joint online softmax over 128 kv (exact rescale-skip) ----
    {
      f32x4 vA = __builtin_elementwise_max(
          __builtin_elementwise_max(sA[0], sA[1]),
          __builtin_elementwise_max(sA[2], sA[3]));
      f32x4 vB = __builtin_elementwise_max(
          __builtin_elementwise_max(sB[0], sB[1]),
          __builtin_elementwise_max(sB[2], sB[3]));
      f32x4 v = __builtin_elementwise_max(vA, vB);
      float pm = fmaxf(fmaxf(v[0], v[1]), fmaxf(v[2], v[3]));
      pm = fmaxf(pm, __shfl_xor(pm, 16));
      pm = fmaxf(pm, __shfl_xor(pm, 32));
      bool need = pm > m_;
      if (__any((int)need)) {              // exact: skipped only when es==1
        float nm = fmaxf(m_, pm);
        float es = ex2(m_ - nm);
        m_ = nm;
        l_ *= es;
#pragma unroll
        for (int r = 0; r < 4; ++r) {
          float esr = __shfl(es, (l4 << 4) + l4 * 4 + r);
#pragma unroll
          for (int dt = 0; dt < 4; ++dt) o_[dt][r] *= esr;
        }
      }
#pragma unroll
      for (int nt = 0; nt < 4; ++nt)
#pragma unroll
        for (int r = 0; r < 4; ++r) {
          sA[nt][r] = ex2(sA[nt][r] - m_);
          sB[nt][r] = ex2(sB[nt][r] - m_);
        }
      f32x4 tsum = (sA[0] + sA[1]) + (sA[2] + sA[3])
                 + (sB[0] + sB[1]) + (sB[2] + sB[3]);
      l_ += (tsum[0] + tsum[1]) + (tsum[2] + tsum[3]);
    }

    // ---- pack P to bf16 pairs ----
    u32 pkA[4][2], pkB[4][2];
#pragma unroll
    for (int nt = 0; nt < 4; ++nt) {
      pkA[nt][0] = (u32)f2bf(sA[nt][0]) | ((u32)f2bf(sA[nt][1]) << 16);
      pkA[nt][1] = (u32)f2bf(sA[nt][2]) | ((u32)f2bf(sA[nt][3]) << 16);
      pkB[nt][0] = (u32)f2bf(sB[nt][0]) | ((u32)f2bf(sB[nt][1]) << 16);
      pkB[nt][1] = (u32)f2bf(sB[nt][2]) | ((u32)f2bf(sB[nt][3]) << 16);
    }

    // ---- O += P V over both halves (bpermute P to A-fragment) ----
#pragma unroll
    for (int half = 0; half < 2; ++half) {
      const char* Vc = half ? VcB : VcA;
      u32 (*pk)[2] = half ? pkB : pkA;
#pragma unroll
      for (int kf = 0; kf < 2; ++kf) {
        u32 w[4];
#pragma unroll
        for (int wi = 0; wi < 4; ++wi) {
          int ad = (wi < 2) ? addrA : addrB;
          u32 lo = __builtin_amdgcn_ds_bpermute(ad, (int)pk[2 * kf][wi & 1]);
          u32 hi = __builtin_amdgcn_ds_bpermute(ad, (int)pk[2 * kf + 1][wi & 1]);
          w[wi] = hiHalf ? hi : lo;
        }
        bf16x8 pa = __builtin_bit_cast(bf16x8, u32x4{w[0], w[1], w[2], w[3]});
        __builtin_amdgcn_s_setprio(1);
#pragma unroll
        for (int dt = 0; dt < 4; ++dt) {
          int d = dt * 16 + l15;
          int slot = ((kf * 4 + l4) ^ (d & 7)) << 4;
          bf16x8 vf = __builtin_bit_cast(bf16x8,
              *(const u32x4*)(Vc + d * 128 + slot));
          o_[dt] = __builtin_amdgcn_mfma_f32_16x16x32_bf16(pa, vf, o_[dt], 0, 0, 0);
        }
        __builtin_amdgcn_s_setprio(0);
      }
    }
  }

  // ---- epilogue: finish l reduce (across l4), normalize, store ----
  float lt = l_ + __shfl_xor(l_, 16);
  lt += __shfl_xor(lt, 32);
  float linv = 1.0f / lt;
  float li4[4];
#pragma unroll
  for (int r = 0; r < 4; ++r)
    li4[r] = __shfl(linv, (l4 << 4) + l4 * 4 + r);

  if (mode == 2) {
#pragma unroll
    for (int dt = 0; dt < 4; ++dt)
#pragma unroll
      for (int r = 0; r < 4; ++r) {
        float val = o_[dt][r] * li4[r];
        int tok = qt * 64 + wid * 16 + l4 * 4 + r;
        O[(((size_t)(b * S_LEN + tok)) << 10) + h * 64 + dt * 16 + l15] = f2bf(val);
      }
  } else {
    const int pslot = (((bh << 4) + (qt - 16)) << 1) + mode;
    u16* pb = pO + ((size_t)pslot << 12);
#pragma unroll
    for (int dt = 0; dt < 4; ++dt)
#pragma unroll
      for (int r = 0; r < 4; ++r) {
        int row = wid * 16 + l4 * 4 + r;
        pb[row * 64 + dt * 16 + l15] = f2bf(o_[dt][r] * li4[r]);
      }
    if (l4 == 0) {                      // m_/lt live at q = l15, uniform in l4
      ML[pslot * 128 + wid * 16 + l15] = m_;
      ML[pslot * 128 + 64 + wid * 16 + l15] = lt;
    }
  }
}

// ---------------------------------------------------------------------------
// Merge the two partials of each qt>=16 q-tile into O.
// ---------------------------------------------------------------------------
__global__ __launch_bounds__(256) void combine(
    const u16* __restrict__ pO, const float* __restrict__ ML,
    u16* __restrict__ O) {
  const int qi = blockIdx.x, bh = blockIdx.y;
  const int b = bh >> 4, h = bh & 15;
  const int t = threadIdx.x;
  const int row = t >> 2, cblk = (t & 3) << 4;      // 16 cols per thread
  const int s0 = (((bh << 4) + qi) << 1), s1 = s0 + 1;
  float m0 = ML[s0 * 128 + row], l0 = ML[s0 * 128 + 64 + row];
  float m1 = ML[s1 * 128 + row], l1 = ML[s1 * 128 + 64 + row];
  float m = fmaxf(m0, m1);
  float w0 = l0 * ex2(m0 - m), w1 = l1 * ex2(m1 - m);
  float inv = 1.0f / (w0 + w1);
  w0 *= inv; w1 *= inv;
  const u16* p0 = pO + (((size_t)s0) << 12) + row * 64 + cblk;
  const u16* p1 = pO + (((size_t)s1) << 12) + row * 64 + cblk;
  const int tok = (16 + qi) * 64 + row;
  u16* dst = O + (((size_t)(b * S_LEN + tok)) << 10) + h * 64 + cblk;
#pragma unroll
  for (int half = 0; half < 2; ++half) {
    u16x8 a = *(const u16x8*)(p0 + half * 8);
    u16x8 c = *(const u16x8*)(p1 + half * 8);
    u16x8 o;
#pragma unroll
    for (int j = 0; j < 8; ++j)
      o[j] = f2bf(w0 * bf2f(a[j]) + w1 * bf2f(c[j]));
    *(u16x8*)(dst + half * 8) = o;
  }
}

// ---------------------------------------------------------------------------
extern "C" void kernel_launch(void* const* d_in, const int* in_sizes, int n_in,
                              void* d_out, int out_size, void* d_ws, size_t ws_size,
                              hipStream_t stream) {
  const float* x    = (const float*)d_in[0];
  const float* Wqkv = (const float*)d_in[1];
  const float* bqkv = (const float*)d_in[2];
  const float* Wout = (const float*)d_in[3];
  const float* bout = (const float*)d_in[4];
  float* out = (float*)d_out;

  // workspace layout (u16 elems): ~51 MiB total
  u16* xb    = (u16*)d_ws;            // 4,194,304   (dead after QKV GEMM)
  u16* wqkvb = xb + 4194304;          // 3,145,728   (dead after QKV GEMM)
  u16* woutb = wqkvb + 3145728;       // 1,048,576
  u16* qkb   = woutb + 1048576;       // 8,388,608  (Q|K, [4096][2048])
  u16* vtb   = qkb + 8388608;         // 4,194,304  (V^T, [32][64][2048])
  u16* ob    = vtb + 4194304;         // 4,194,304
  // attention partials alias the dead xb/wqkvb regions:
  u16*   pO = xb;                     // 1024 slots x 64x64 bf16 = 4,194,304 u16
  float* ML = (float*)wqkvb;          // 1024 slots x 128 f32    = 131,072 f32

  f2bf_all<<<2048, 256, 0, stream>>>(x, Wqkv, Wout, xb, wqkvb, woutb);

  gemm_bt<2><<<dim3(24, 32), 256, 0, stream>>>(xb, wqkvb, bqkv, qkb, vtb,
                                               4096, 3072, 1024, 0);
  attn9<<<dim3(48, 32), 256, 0, stream>>>(qkb, vtb, ob, pO, ML);
  combine<<<dim3(16, 32), 256, 0, stream>>>(pO, ML, ob);
  gemm_bt<0><<<dim3(8, 32), 256, 0, stream>>>(ob, woutb, bout, out, nullptr,
                                              4096, 1024, 1024, 1024);
}

// Round 13
// 149.881 us; speedup vs baseline: 1.7318x; 1.0616x over previous
//
#include <hip/hip_runtime.h>
#include <hip/hip_bf16.h>
#include <stdint.h>

typedef unsigned short u16;
typedef unsigned int u32;
typedef __attribute__((ext_vector_type(8))) __bf16 bf16x8;
typedef __attribute__((ext_vector_type(8))) u16 u16x8;
typedef __attribute__((ext_vector_type(4))) u16 u16x4;
typedef __attribute__((ext_vector_type(4))) float f32x4;
typedef __attribute__((ext_vector_type(4))) u32 u32x4;
typedef __attribute__((ext_vector_type(2))) u32 u32x2;

#define S_LEN 2048
#define QSCALE 0.180336880f   /* (1/8) * log2(e) */

__device__ __forceinline__ u16 f2bf(float f) {
  u32 u = __builtin_bit_cast(u32, f);
  u32 r = u + 0x7fffu + ((u >> 16) & 1u);   // round-to-nearest-even
  return (u16)(r >> 16);
}
__device__ __forceinline__ float bf2f(u16 h) {
  u32 u = ((u32)h) << 16;
  return __builtin_bit_cast(float, u);
}
__device__ __forceinline__ float ex2(float x) { return __builtin_exp2f(x); }

__device__ __forceinline__ void gload_lds16(const void* g, void* l) {
  __builtin_amdgcn_global_load_lds(
      (const __attribute__((address_space(1))) void*)g,
      (__attribute__((address_space(3))) void*)l, 16, 0, 0);
}

// ---------------------------------------------------------------------------
// fused fp32 -> bf16 conversion of x | Wqkv | Wout (one launch)
// ---------------------------------------------------------------------------
#define N4_X 1048576
#define N4_WQKV 786432
#define N4_WOUT 262144
__global__ void f2bf_all(const float* __restrict__ x, const float* __restrict__ wq,
                         const float* __restrict__ wo, u16* __restrict__ xb,
                         u16* __restrict__ wqb, u16* __restrict__ wob) {
  int i = blockIdx.x * blockDim.x + threadIdx.x;
  int stride = gridDim.x * blockDim.x;
  const int total = N4_X + N4_WQKV + N4_WOUT;
  for (; i < total; i += stride) {
    const float4* src; ushort4* dst; int k;
    if (i < N4_X) { src = (const float4*)x; dst = (ushort4*)xb; k = i; }
    else if (i < N4_X + N4_WQKV) { src = (const float4*)wq; dst = (ushort4*)wqb; k = i - N4_X; }
    else { src = (const float4*)wo; dst = (ushort4*)wob; k = i - N4_X - N4_WQKV; }
    float4 v = src[k];
    ushort4 o;
    o.x = f2bf(v.x); o.y = f2bf(v.y); o.z = f2bf(v.z); o.w = f2bf(v.w);
    dst[k] = o;
  }
}

// ---------------------------------------------------------------------------
// C = A * B^T + bias.  A:[M,K] bf16, B:[N,K] bf16 (row-major, K contig).
// 128x128 tile, BK=32, 4 waves (2x2). MODE 0: fp32 C0 (ldc).
// MODE 2: QKV split — cols<1024 (Q) -> bf16 C0, scaled by QSCALE;
//         cols in [1024,2048) (K) -> bf16 C0 (ld 2048); cols>=2048 (V) ->
//         transposed bf16 C1 as vt[b*16+h][d][s] (packed 4-row stores).
// ---------------------------------------------------------------------------
template<int MODE>
__global__ __launch_bounds__(256) void gemm_bt(
    const u16* __restrict__ A, const u16* __restrict__ B,
    const float* __restrict__ bias, void* __restrict__ C0,
    u16* __restrict__ C1, int M, int N, int K, int ldc) {
  __shared__ __align__(16) u16 As[128 * 32];
  __shared__ __align__(16) u16 Bs[128 * 32];
  const int tid = threadIdx.x;
  const int wid = tid >> 6, lane = tid & 63;
  const int l15 = lane & 15, l4 = lane >> 4;
  const int wr = wid >> 1, wc = wid & 1;
  const int bm = blockIdx.y * 128, bn = blockIdx.x * 128;

  f32x4 acc[4][4] = {};

  for (int k0 = 0; k0 < K; k0 += 32) {
#pragma unroll
    for (int i = 0; i < 2; ++i) {
      int c = i * 256 + wid * 64 + lane;              // chunk id (16B each)
      int row = c >> 2, kc = c & 3;
      gload_lds16(A + (size_t)(bm + row) * K + k0 + kc * 8,
                  (char*)As + (i * 256 + wid * 64) * 16);
      gload_lds16(B + (size_t)(bn + row) * K + k0 + kc * 8,
                  (char*)Bs + (i * 256 + wid * 64) * 16);
    }
    __syncthreads();

    bf16x8 a[4], b[4];
#pragma unroll
    for (int mi = 0; mi < 4; ++mi)
      a[mi] = __builtin_bit_cast(bf16x8,
          *(const u32x4*)&As[(wr * 64 + mi * 16 + l15) * 32 + l4 * 8]);
#pragma unroll
    for (int ni = 0; ni < 4; ++ni)
      b[ni] = __builtin_bit_cast(bf16x8,
          *(const u32x4*)&Bs[(wc * 64 + ni * 16 + l15) * 32 + l4 * 8]);
#pragma unroll
    for (int mi = 0; mi < 4; ++mi)
#pragma unroll
      for (int ni = 0; ni < 4; ++ni)
        acc[mi][ni] = __builtin_amdgcn_mfma_f32_16x16x32_bf16(
            a[mi], b[ni], acc[mi][ni], 0, 0, 0);
    __syncthreads();
  }

#pragma unroll
  for (int ni = 0; ni < 4; ++ni) {
    int col = bn + wc * 64 + ni * 16 + l15;
    float bv = bias[col];
#pragma unroll
    for (int mi = 0; mi < 4; ++mi) {
      int row = bm + wr * 64 + mi * 16 + l4 * 4;
      if (MODE == 0) {
#pragma unroll
        for (int r = 0; r < 4; ++r)
          ((float*)C0)[(size_t)(row + r) * ldc + col] = acc[mi][ni][r] + bv;
      } else {
        if (col < 2048) {
          float sc = (col < 1024) ? QSCALE : 1.0f;
#pragma unroll
          for (int r = 0; r < 4; ++r)
            ((u16*)C0)[(size_t)(row + r) * 2048 + col] = f2bf((acc[mi][ni][r] + bv) * sc);
        } else {
          u16x4 vv;
#pragma unroll
          for (int r = 0; r < 4; ++r) vv[r] = f2bf(acc[mi][ni][r] + bv);
          int hh = (col - 2048) >> 6, d = (col - 2048) & 63;
          int bb = row >> 11, s = row & 2047;
          *(u16x4*)&C1[(((size_t)(bb * 16 + hh) * 64 + d) << 11) + s] = vv;
        }
      }
    }
  }
}

// ---------------------------------------------------------------------------
// Causal flash attention, split-KV grid (r9), swapped QK^T, with IN-BLOCK
// 2x2 work split: wave (qh,kvh) computes a 32q x 32kv partial stream with
// private (m,l,o). kv-half=32 puts P exactly in the PV A-fragment layout
// (k-slot pi(8*l4+j) = {4l4+j, 16+4l4+j}) -> ZERO bpermutes, 3x fewer LDS
// reads. Epilogue: 2-way in-block flash-merge via LDS, then r9's unchanged
// direct/partial global paths. Staging/dbuf/barriers byte-identical to r9.
// ---------------------------------------------------------------------------
__global__ __launch_bounds__(256, 4) void attn10(
    const u16* __restrict__ qk, const u16* __restrict__ vt,
    u16* __restrict__ O, u16* __restrict__ pO, float* __restrict__ ML) {
  __shared__ __align__(16) u16 SM[2][2][64 * 64];   // [buf][K=0/V=1][8KB]
  __shared__ float MLsh[4][64];                     // [wave][32 m | 32 l]
  const int tid = threadIdx.x;
  const int wid = tid >> 6, lane = tid & 63;
  const int l15 = lane & 15, l4 = lane >> 4;
  const int qh = wid >> 1, kvh = wid & 1;
  const int i = blockIdx.x, bh = blockIdx.y;
  const int b = bh >> 4, h = bh & 15;

  // decode (qt, kt-range, mode); ordered roughly longest-first (r9)
  int qt, k0t, mode;
  if (i < 16)      { qt = 16 + i;  k0t = 0;  mode = 0; }   // part0
  else if (i < 32) { qt = 47 - i;  k0t = 16; mode = 1; }   // part1
  else             { qt = 47 - i;  k0t = 0;  mode = 2; }   // single
  const int k1t = (mode == 0) ? 15 : qt;

  const u16* qkb = qk + (((size_t)b * S_LEN) << 11);
  const u16* vtb = vt + ((size_t)bh << 17);           // 64*2048 per (b,h)
  const int qcol = h * 64, kcol = 1024 + h * 64;

  // staging chunk descriptors (r9): chunk c -> row r = c>>3, swizzled col
  const int c0 = tid, c1 = 256 + tid;
  const int r0 = c0 >> 3, sw0 = ((c0 & 7) ^ (r0 & 7)) << 3;
  const int r1 = c1 >> 3, sw1 = ((c1 & 7) ^ (r1 & 7)) << 3;

  auto stage = [&](int buf, int kt) {
    int kvb = kt << 6;
    gload_lds16(qkb + (((size_t)(kvb + r0)) << 11) + kcol + sw0, (char*)&SM[buf][0][0] + c0 * 16);
    gload_lds16(qkb + (((size_t)(kvb + r1)) << 11) + kcol + sw1, (char*)&SM[buf][0][0] + c1 * 16);
    gload_lds16(vtb + ((size_t)r0 << 11) + kvb + sw0, (char*)&SM[buf][1][0] + c0 * 16);
    gload_lds16(vtb + ((size_t)r1 << 11) + kvb + sw1, (char*)&SM[buf][1][0] + c1 * 16);
  };

  // Q fragments (B-op): 2 q-subtiles x 2 kf; rows qt*64 + qh*32 + qs*16 + l15
  bf16x8 qf[2][2];
#pragma unroll
  for (int qs = 0; qs < 2; ++qs)
#pragma unroll
    for (int kf = 0; kf < 2; ++kf) {
      int rq = qt * 64 + qh * 32 + qs * 16 + l15;
      qf[qs][kf] = __builtin_bit_cast(bf16x8,
          *(const u16x8*)&qkb[((size_t)rq << 11) + qcol + kf * 32 + l4 * 8]);
    }
  const int qpos0 = qt * 64 + qh * 32 + l15;   // + qs*16 per subtile

  float m_[2] = {-1.0e30f, -1.0e30f};
  float l_[2] = {0.f, 0.f};
  f32x4 o_[2][4] = {};

  stage(0, k0t);
  for (int kt = k0t; kt <= k1t; ++kt) {
    const int kvb = kt << 6;
    const int cur = (kt - k0t) & 1;
    __syncthreads();                       // drains stage(cur); guards reuse
    if (kt < k1t) stage(cur ^ 1, kt + 1);  // prefetch next tile

    const char* Kc = (const char*)&SM[cur][0][0];
    const char* Vc = (const char*)&SM[cur][1][0];

    // ---- S^T = K Q^T on this wave's 32-kv half x 32-q half ----
    // s[qs][nt]: q = l15 (in subtile qs), kv = kvh*32 + nt*16 + l4*4 + r
    f32x4 s[2][2] = {};
#pragma unroll
    for (int kf = 0; kf < 2; ++kf)
#pragma unroll
      for (int nt = 0; nt < 2; ++nt) {
        int row = kvh * 32 + nt * 16 + l15;
        int slot = (kf * 4 + l4) ^ (l15 & 7);
        bf16x8 kf8 = __builtin_bit_cast(bf16x8,
            *(const u32x4*)(Kc + row * 128 + (slot << 4)));
        s[0][nt] = __builtin_amdgcn_mfma_f32_16x16x32_bf16(kf8, qf[0][kf], s[0][nt], 0, 0, 0);
        s[1][nt] = __builtin_amdgcn_mfma_f32_16x16x32_bf16(kf8, qf[1][kf], s[1][nt], 0, 0, 0);
      }

    // ---- causal mask (diagonal tile only) ----
    if (kt == qt) {
#pragma unroll
      for (int qs = 0; qs < 2; ++qs)
#pragma unroll
        for (int nt = 0; nt < 2; ++nt) {
          int kvr = kvb + kvh * 32 + nt * 16 + l4 * 4;
          int qp = qpos0 + qs * 16;
#pragma unroll
          for (int r = 0; r < 4; ++r)
            if (kvr + r > qp) s[qs][nt][r] = -__builtin_inff();
        }
    }

    // ---- online softmax per q-subtile (exact rescale-skip) ----
    {
      float pm[2];
#pragma unroll
      for (int qs = 0; qs < 2; ++qs) {
        f32x4 v = __builtin_elementwise_max(s[qs][0], s[qs][1]);
        float p = fmaxf(fmaxf(v[0], v[1]), fmaxf(v[2], v[3]));
        p = fmaxf(p, __shfl_xor(p, 16));
        p = fmaxf(p, __shfl_xor(p, 32));
        pm[qs] = p;
      }
      bool need = (pm[0] > m_[0]) | (pm[1] > m_[1]);
      if (__any((int)need)) {
        float es[2];
#pragma unroll
        for (int qs = 0; qs < 2; ++qs) {
          float nm = fmaxf(m_[qs], pm[qs]);
          es[qs] = ex2(m_[qs] - nm);
          m_[qs] = nm;
          l_[qs] *= es[qs];
        }
#pragma unroll
        for (int r = 0; r < 4; ++r) {
          float e0 = __shfl(es[0], l4 * 4 + r);
          float e1 = __shfl(es[1], l4 * 4 + r);
#pragma unroll
          for (int dt = 0; dt < 4; ++dt) {
            o_[0][dt][r] *= e0;
            o_[1][dt][r] *= e1;
          }
        }
      }
#pragma unroll
      for (int qs = 0; qs < 2; ++qs) {
#pragma unroll
        for (int nt = 0; nt < 2; ++nt)
#pragma unroll
          for (int r = 0; r < 4; ++r)
            s[qs][nt][r] = ex2(s[qs][nt][r] - m_[qs]);
        l_[qs] += ((s[qs][0][0] + s[qs][0][1]) + (s[qs][0][2] + s[qs][0][3]))
                + ((s[qs][1][0] + s[qs][1][1]) + (s[qs][1][2] + s[qs][1][3]));
      }
    }

    // ---- pack P into A-fragment directly (k-slot pi: in-lane!) ----
    bf16x8 pa[2];
#pragma unroll
    for (int qs = 0; qs < 2; ++qs) {
      u32 w0 = (u32)f2bf(s[qs][0][0]) | ((u32)f2bf(s[qs][0][1]) << 16);
      u32 w1 = (u32)f2bf(s[qs][0][2]) | ((u32)f2bf(s[qs][0][3]) << 16);
      u32 w2 = (u32)f2bf(s[qs][1][0]) | ((u32)f2bf(s[qs][1][1]) << 16);
      u32 w3 = (u32)f2bf(s[qs][1][2]) | ((u32)f2bf(s[qs][1][3]) << 16);
      pa[qs] = __builtin_bit_cast(bf16x8, u32x4{w0, w1, w2, w3});
    }

    // ---- O += P V (V B-op reads matching pi granules; 2-way max conflict) --
    const int gc0 = kvh * 4 + (l4 >> 1);
    const int hb = (l4 & 1) * 8;
    const int sx = l15 & 7;
#pragma unroll
    for (int dt = 0; dt < 4; ++dt) {
      int d = dt * 16 + l15;
      const char* rowp = Vc + d * 128 + hb;
      u32x2 vlo = *(const u32x2*)(rowp + ((gc0 ^ sx) << 4));
      u32x2 vhi = *(const u32x2*)(rowp + (((gc0 + 2) ^ sx) << 4));
      bf16x8 vf = __builtin_bit_cast(bf16x8, u32x4{vlo[0], vlo[1], vhi[0], vhi[1]});
      o_[0][dt] = __builtin_amdgcn_mfma_f32_16x16x32_bf16(pa[0], vf, o_[0][dt], 0, 0, 0);
      o_[1][dt] = __builtin_amdgcn_mfma_f32_16x16x32_bf16(pa[1], vf, o_[1][dt], 0, 0, 0);
    }
  }

  // ---- finish per-wave l across l4 ----
  float lt0 = l_[0] + __shfl_xor(l_[0], 16); lt0 += __shfl_xor(lt0, 32);
  float lt1 = l_[1] + __shfl_xor(l_[1], 16); lt1 += __shfl_xor(lt1, 32);

  // ---- in-block 2-way merge via LDS (K/V buffers are dead now) ----
  __syncthreads();
  u16* pw = (u16*)SM + wid * 2048;               // 32q x 64d bf16 per wave
#pragma unroll
  for (int qs = 0; qs < 2; ++qs)
#pragma unroll
    for (int dt = 0; dt < 4; ++dt)
#pragma unroll
      for (int r = 0; r < 4; ++r)
        pw[(qs * 16 + l4 * 4 + r) * 64 + dt * 16 + l15] = f2bf(o_[qs][dt][r]);
  if (l4 == 0) {
    MLsh[wid][l15]      = m_[0];  MLsh[wid][32 + l15] = lt0;
    MLsh[wid][16 + l15] = m_[1];  MLsh[wid][48 + l15] = lt1;
  }
  __syncthreads();

  // wave wid finalizes rows q = wid*16 + l4*4 + r (q-half = wid>>1)
  const int wA = (wid >> 1) << 1, wB = wA + 1;
  const u16* pA = (const u16*)SM + wA * 2048;
  const u16* pB = (const u16*)SM + wB * 2048;
  float wtA[4], wtB[4], inv[4], Mx[4], Lx[4];
  int qlr[4];
#pragma unroll
  for (int r = 0; r < 4; ++r) {
    int ql = (wid & 1) * 16 + l4 * 4 + r;
    qlr[r] = ql;
    float mA = MLsh[wA][ql], lA = MLsh[wA][32 + ql];
    float mB = MLsh[wB][ql], lB = MLsh[wB][32 + ql];
    float M2 = fmaxf(mA, mB);
    float a = ex2(mA - M2), bb = ex2(mB - M2);
    float L = lA * a + lB * bb;
    Mx[r] = M2; Lx[r] = L;
    wtA[r] = a; wtB[r] = bb;
    inv[r] = 1.0f / L;
  }

  if (mode == 2) {
#pragma unroll
    for (int dt = 0; dt < 4; ++dt)
#pragma unroll
      for (int r = 0; r < 4; ++r) {
        int idx = qlr[r] * 64 + dt * 16 + l15;
        float val = (bf2f(pA[idx]) * wtA[r] + bf2f(pB[idx]) * wtB[r]) * inv[r];
        int tok = qt * 64 + wid * 16 + l4 * 4 + r;
        O[(((size_t)(b * S_LEN + tok)) << 10) + h * 64 + dt * 16 + l15] = f2bf(val);
      }
  } else {
    const int pslot = (((bh << 4) + (qt - 16)) << 1) + mode;
    u16* pb = pO + ((size_t)pslot << 12);
#pragma unroll
    for (int dt = 0; dt < 4; ++dt)
#pragma unroll
      for (int r = 0; r < 4; ++r) {
        int idx = qlr[r] * 64 + dt * 16 + l15;
        float val = (bf2f(pA[idx]) * wtA[r] + bf2f(pB[idx]) * wtB[r]) * inv[r];
        int row = wid * 16 + l4 * 4 + r;
        pb[row * 64 + dt * 16 + l15] = f2bf(val);
      }
    if (l15 == 0) {
#pragma unroll
      for (int r = 0; r < 4; ++r) {
        int row = wid * 16 + l4 * 4 + r;
        ML[pslot * 128 + row] = Mx[r];
        ML[pslot * 128 + 64 + row] = Lx[r];
      }
    }
  }
}

// ---------------------------------------------------------------------------
// Merge the two partials of each qt>=16 q-tile into O. (unchanged r9)
// ---------------------------------------------------------------------------
__global__ __launch_bounds__(256) void combine(
    const u16* __restrict__ pO, const float* __restrict__ ML,
    u16* __restrict__ O) {
  const int qi = blockIdx.x, bh = blockIdx.y;
  const int b = bh >> 4, h = bh & 15;
  const int t = threadIdx.x;
  const int row = t >> 2, cblk = (t & 3) << 4;      // 16 cols per thread
  const int s0 = (((bh << 4) + qi) << 1), s1 = s0 + 1;
  float m0 = ML[s0 * 128 + row], l0 = ML[s0 * 128 + 64 + row];
  float m1 = ML[s1 * 128 + row], l1 = ML[s1 * 128 + 64 + row];
  float m = fmaxf(m0, m1);
  float w0 = l0 * ex2(m0 - m), w1 = l1 * ex2(m1 - m);
  float inv = 1.0f / (w0 + w1);
  w0 *= inv; w1 *= inv;
  const u16* p0 = pO + (((size_t)s0) << 12) + row * 64 + cblk;
  const u16* p1 = pO + (((size_t)s1) << 12) + row * 64 + cblk;
  const int tok = (16 + qi) * 64 + row;
  u16* dst = O + (((size_t)(b * S_LEN + tok)) << 10) + h * 64 + cblk;
#pragma unroll
  for (int half = 0; half < 2; ++half) {
    u16x8 a = *(const u16x8*)(p0 + half * 8);
    u16x8 c = *(const u16x8*)(p1 + half * 8);
    u16x8 o;
#pragma unroll
    for (int j = 0; j < 8; ++j)
      o[j] = f2bf(w0 * bf2f(a[j]) + w1 * bf2f(c[j]));
    *(u16x8*)(dst + half * 8) = o;
  }
}

// ---------------------------------------------------------------------------
extern "C" void kernel_launch(void* const* d_in, const int* in_sizes, int n_in,
                              void* d_out, int out_size, void* d_ws, size_t ws_size,
                              hipStream_t stream) {
  const float* x    = (const float*)d_in[0];
  const float* Wqkv = (const float*)d_in[1];
  const float* bqkv = (const float*)d_in[2];
  const float* Wout = (const float*)d_in[3];
  const float* bout = (const float*)d_in[4];
  float* out = (float*)d_out;

  // workspace layout (u16 elems): ~51 MiB total
  u16* xb    = (u16*)d_ws;            // 4,194,304   (dead after QKV GEMM)
  u16* wqkvb = xb + 4194304;          // 3,145,728   (dead after QKV GEMM)
  u16* woutb = wqkvb + 3145728;       // 1,048,576
  u16* qkb   = woutb + 1048576;       // 8,388,608  (Q|K, [4096][2048])
  u16* vtb   = qkb + 8388608;         // 4,194,304  (V^T, [32][64][2048])
  u16* ob    = vtb + 4194304;         // 4,194,304
  // attention partials alias the dead xb/wqkvb regions:
  u16*   pO = xb;                     // 1024 slots x 64x64 bf16 = 4,194,304 u16
  float* ML = (float*)wqkvb;          // 1024 slots x 128 f32    = 131,072 f32

  f2bf_all<<<2048, 256, 0, stream>>>(x, Wqkv, Wout, xb, wqkvb, woutb);

  gemm_bt<2><<<dim3(24, 32), 256, 0, stream>>>(xb, wqkvb, bqkv, qkb, vtb,
                                               4096, 3072, 1024, 0);
  attn10<<<dim3(48, 32), 256, 0, stream>>>(qkb, vtb, ob, pO, ML);
  combine<<<dim3(16, 32), 256, 0, stream>>>(pO, ML, ob);
  gemm_bt<0><<<dim3(8, 32), 256, 0, stream>>>(ob, woutb, bout, out, nullptr,
                                              4096, 1024, 1024, 1024);
}

// Round 14
// 145.717 us; speedup vs baseline: 1.7813x; 1.0286x over previous
//
#include <hip/hip_runtime.h>
#include <hip/hip_bf16.h>
#include <stdint.h>

typedef unsigned short u16;
typedef unsigned int u32;
typedef __attribute__((ext_vector_type(8))) __bf16 bf16x8;
typedef __attribute__((ext_vector_type(8))) u16 u16x8;
typedef __attribute__((ext_vector_type(4))) u16 u16x4;
typedef __attribute__((ext_vector_type(4))) float f32x4;
typedef __attribute__((ext_vector_type(4))) u32 u32x4;
typedef __attribute__((ext_vector_type(2))) u32 u32x2;

#define S_LEN 2048
#define QSCALE 0.180336880f   /* (1/8) * log2(e) */

__device__ __forceinline__ u16 f2bf(float f) {
  u32 u = __builtin_bit_cast(u32, f);
  u32 r = u + 0x7fffu + ((u >> 16) & 1u);   // round-to-nearest-even
  return (u16)(r >> 16);
}
__device__ __forceinline__ float bf2f(u16 h) {
  u32 u = ((u32)h) << 16;
  return __builtin_bit_cast(float, u);
}
__device__ __forceinline__ float ex2(float x) { return __builtin_exp2f(x); }

__device__ __forceinline__ void gload_lds16(const void* g, void* l) {
  __builtin_amdgcn_global_load_lds(
      (const __attribute__((address_space(1))) void*)g,
      (__attribute__((address_space(3))) void*)l, 16, 0, 0);
}

// ---------------------------------------------------------------------------
// fused fp32 -> bf16 conversion of x | Wqkv | Wout (one launch)
// ---------------------------------------------------------------------------
#define N4_X 1048576
#define N4_WQKV 786432
#define N4_WOUT 262144
__global__ void f2bf_all(const float* __restrict__ x, const float* __restrict__ wq,
                         const float* __restrict__ wo, u16* __restrict__ xb,
                         u16* __restrict__ wqb, u16* __restrict__ wob) {
  int i = blockIdx.x * blockDim.x + threadIdx.x;
  int stride = gridDim.x * blockDim.x;
  const int total = N4_X + N4_WQKV + N4_WOUT;
  for (; i < total; i += stride) {
    const float4* src; ushort4* dst; int k;
    if (i < N4_X) { src = (const float4*)x; dst = (ushort4*)xb; k = i; }
    else if (i < N4_X + N4_WQKV) { src = (const float4*)wq; dst = (ushort4*)wqb; k = i - N4_X; }
    else { src = (const float4*)wo; dst = (ushort4*)wob; k = i - N4_X - N4_WQKV; }
    float4 v = src[k];
    ushort4 o;
    o.x = f2bf(v.x); o.y = f2bf(v.y); o.z = f2bf(v.z); o.w = f2bf(v.w);
    dst[k] = o;
  }
}

// ---------------------------------------------------------------------------
// C = A * B^T + bias.  A:[M,K] bf16, B:[N,K] bf16 (row-major, K contig).
// 128x128 tile, BK=32, 4 waves (2x2). MODE 0: fp32 C0 (ldc).
// MODE 2: QKV split — cols<1024 (Q) -> bf16 C0, scaled by QSCALE;
//         cols in [1024,2048) (K) -> bf16 C0 (ld 2048); cols>=2048 (V) ->
//         transposed bf16 C1 as vt[b*16+h][d][s] (packed 4-row stores).
// ---------------------------------------------------------------------------
template<int MODE>
__global__ __launch_bounds__(256) void gemm_bt(
    const u16* __restrict__ A, const u16* __restrict__ B,
    const float* __restrict__ bias, void* __restrict__ C0,
    u16* __restrict__ C1, int M, int N, int K, int ldc) {
  __shared__ __align__(16) u16 As[128 * 32];
  __shared__ __align__(16) u16 Bs[128 * 32];
  const int tid = threadIdx.x;
  const int wid = tid >> 6, lane = tid & 63;
  const int l15 = lane & 15, l4 = lane >> 4;
  const int wr = wid >> 1, wc = wid & 1;
  const int bm = blockIdx.y * 128, bn = blockIdx.x * 128;

  f32x4 acc[4][4] = {};

  for (int k0 = 0; k0 < K; k0 += 32) {
#pragma unroll
    for (int i = 0; i < 2; ++i) {
      int c = i * 256 + wid * 64 + lane;              // chunk id (16B each)
      int row = c >> 2, kc = c & 3;
      gload_lds16(A + (size_t)(bm + row) * K + k0 + kc * 8,
                  (char*)As + (i * 256 + wid * 64) * 16);
      gload_lds16(B + (size_t)(bn + row) * K + k0 + kc * 8,
                  (char*)Bs + (i * 256 + wid * 64) * 16);
    }
    __syncthreads();

    bf16x8 a[4], b[4];
#pragma unroll
    for (int mi = 0; mi < 4; ++mi)
      a[mi] = __builtin_bit_cast(bf16x8,
          *(const u32x4*)&As[(wr * 64 + mi * 16 + l15) * 32 + l4 * 8]);
#pragma unroll
    for (int ni = 0; ni < 4; ++ni)
      b[ni] = __builtin_bit_cast(bf16x8,
          *(const u32x4*)&Bs[(wc * 64 + ni * 16 + l15) * 32 + l4 * 8]);
#pragma unroll
    for (int mi = 0; mi < 4; ++mi)
#pragma unroll
      for (int ni = 0; ni < 4; ++ni)
        acc[mi][ni] = __builtin_amdgcn_mfma_f32_16x16x32_bf16(
            a[mi], b[ni], acc[mi][ni], 0, 0, 0);
    __syncthreads();
  }

#pragma unroll
  for (int ni = 0; ni < 4; ++ni) {
    int col = bn + wc * 64 + ni * 16 + l15;
    float bv = bias[col];
#pragma unroll
    for (int mi = 0; mi < 4; ++mi) {
      int row = bm + wr * 64 + mi * 16 + l4 * 4;
      if (MODE == 0) {
#pragma unroll
        for (int r = 0; r < 4; ++r)
          ((float*)C0)[(size_t)(row + r) * ldc + col] = acc[mi][ni][r] + bv;
      } else {
        if (col < 2048) {
          float sc = (col < 1024) ? QSCALE : 1.0f;
#pragma unroll
          for (int r = 0; r < 4; ++r)
            ((u16*)C0)[(size_t)(row + r) * 2048 + col] = f2bf((acc[mi][ni][r] + bv) * sc);
        } else {
          u16x4 vv;
#pragma unroll
          for (int r = 0; r < 4; ++r) vv[r] = f2bf(acc[mi][ni][r] + bv);
          int hh = (col - 2048) >> 6, d = (col - 2048) & 63;
          int bb = row >> 11, s = row & 2047;
          *(u16x4*)&C1[(((size_t)(bb * 16 + hh) * 64 + d) << 11) + s] = vv;
        }
      }
    }
  }
}

// ---------------------------------------------------------------------------
// Causal flash attention (r13 compute, 2x2 in-block split) with:
//  - XCD-locality swizzle: all 48 blocks of a bh pinned to one XCD
//    (bh working set 4 x 512KB = 2MB fits the 4MB per-XCD L2)
//  - depth-2 counted-vmcnt pipeline: 3 staging buffers, raw s_barrier +
//    vmcnt(4) (vmcnt(0) only on the last iteration) — staging latency
//    off the critical path. Each wave waits its own 4 tile-loads before
//    the barrier => all tile data visible to all waves after it.
// ---------------------------------------------------------------------------
__global__ __launch_bounds__(256, 3) void attn11(
    const u16* __restrict__ qk, const u16* __restrict__ vt,
    u16* __restrict__ O, u16* __restrict__ pO, float* __restrict__ ML) {
  __shared__ __align__(16) u16 SM[3][2][64 * 64];   // [buf][K=0/V=1][8KB]
  __shared__ float MLsh[4][64];                     // [wave][32 m | 32 l]
  const int tid = threadIdx.x;
  const int wid = tid >> 6, lane = tid & 63;
  const int l15 = lane & 15, l4 = lane >> 4;
  const int qh = wid >> 1, kvh = wid & 1;

  // ---- XCD-locality decode: 1536 blocks; bid%8 = XCD (round-robin) ----
  const int bid = blockIdx.x;
  const int xcd = bid & 7, slot = bid >> 3;         // slot in 0..191
  const int bh = xcd * 4 + slot / 48;
  const int i = slot % 48;
  const int b = bh >> 4, h = bh & 15;

  // decode (qt, kt-range, mode); ordered roughly longest-first (r9)
  int qt, k0t, mode;
  if (i < 16)      { qt = 16 + i;  k0t = 0;  mode = 0; }   // part0
  else if (i < 32) { qt = 47 - i;  k0t = 16; mode = 1; }   // part1
  else             { qt = 47 - i;  k0t = 0;  mode = 2; }   // single
  const int k1t = (mode == 0) ? 15 : qt;
  const int n = k1t - k0t + 1;

  const u16* qkb = qk + (((size_t)b * S_LEN) << 11);
  const u16* vtb = vt + ((size_t)bh << 17);           // 64*2048 per (b,h)
  const int qcol = h * 64, kcol = 1024 + h * 64;

  // staging chunk descriptors (r9): chunk c -> row r = c>>3, swizzled col
  const int c0 = tid, c1 = 256 + tid;
  const int r0 = c0 >> 3, sw0 = ((c0 & 7) ^ (r0 & 7)) << 3;
  const int r1 = c1 >> 3, sw1 = ((c1 & 7) ^ (r1 & 7)) << 3;

  auto stage = [&](int buf, int kt) {
    int kvb = kt << 6;
    gload_lds16(qkb + (((size_t)(kvb + r0)) << 11) + kcol + sw0, (char*)&SM[buf][0][0] + c0 * 16);
    gload_lds16(qkb + (((size_t)(kvb + r1)) << 11) + kcol + sw1, (char*)&SM[buf][0][0] + c1 * 16);
    gload_lds16(vtb + ((size_t)r0 << 11) + kvb + sw0, (char*)&SM[buf][1][0] + c0 * 16);
    gload_lds16(vtb + ((size_t)r1 << 11) + kvb + sw1, (char*)&SM[buf][1][0] + c1 * 16);
  };

  // Q fragments (B-op): 2 q-subtiles x 2 kf; rows qt*64 + qh*32 + qs*16 + l15
  bf16x8 qf[2][2];
#pragma unroll
  for (int qs = 0; qs < 2; ++qs)
#pragma unroll
    for (int kf = 0; kf < 2; ++kf) {
      int rq = qt * 64 + qh * 32 + qs * 16 + l15;
      qf[qs][kf] = __builtin_bit_cast(bf16x8,
          *(const u16x8*)&qkb[((size_t)rq << 11) + qcol + kf * 32 + l4 * 8]);
    }
  const int qpos0 = qt * 64 + qh * 32 + l15;   // + qs*16 per subtile

  float m_[2] = {-1.0e30f, -1.0e30f};
  float l_[2] = {0.f, 0.f};
  f32x4 o_[2][4] = {};

  stage(0, k0t);
  if (n > 1) stage(1, k0t + 1);

  for (int idx = 0; idx < n; ++idx) {
    const int kt = k0t + idx;
    const int kvb = kt << 6;
    // own tile's 4 loads complete before barrier; deeper loads stay in flight
    if (idx == n - 1) asm volatile("s_waitcnt vmcnt(0)" ::: "memory");
    else              asm volatile("s_waitcnt vmcnt(4)" ::: "memory");
    __builtin_amdgcn_s_barrier();
    if (idx + 2 < n) stage((idx + 2) % 3, kt + 2);   // depth-2 prefetch
    const int cur = idx % 3;

    const char* Kc = (const char*)&SM[cur][0][0];
    const char* Vc = (const char*)&SM[cur][1][0];

    // ---- S^T = K Q^T on this wave's 32-kv half x 32-q half ----
    f32x4 s[2][2] = {};
#pragma unroll
    for (int kf = 0; kf < 2; ++kf)
#pragma unroll
      for (int nt = 0; nt < 2; ++nt) {
        int row = kvh * 32 + nt * 16 + l15;
        int slot2 = (kf * 4 + l4) ^ (l15 & 7);
        bf16x8 kf8 = __builtin_bit_cast(bf16x8,
            *(const u32x4*)(Kc + row * 128 + (slot2 << 4)));
        s[0][nt] = __builtin_amdgcn_mfma_f32_16x16x32_bf16(kf8, qf[0][kf], s[0][nt], 0, 0, 0);
        s[1][nt] = __builtin_amdgcn_mfma_f32_16x16x32_bf16(kf8, qf[1][kf], s[1][nt], 0, 0, 0);
      }

    // ---- causal mask (diagonal tile only) ----
    if (kt == qt) {
#pragma unroll
      for (int qs = 0; qs < 2; ++qs)
#pragma unroll
        for (int nt = 0; nt < 2; ++nt) {
          int kvr = kvb + kvh * 32 + nt * 16 + l4 * 4;
          int qp = qpos0 + qs * 16;
#pragma unroll
          for (int r = 0; r < 4; ++r)
            if (kvr + r > qp) s[qs][nt][r] = -__builtin_inff();
        }
    }

    // ---- online softmax per q-subtile (exact rescale-skip) ----
    {
      float pm[2];
#pragma unroll
      for (int qs = 0; qs < 2; ++qs) {
        f32x4 v = __builtin_elementwise_max(s[qs][0], s[qs][1]);
        float p = fmaxf(fmaxf(v[0], v[1]), fmaxf(v[2], v[3]));
        p = fmaxf(p, __shfl_xor(p, 16));
        p = fmaxf(p, __shfl_xor(p, 32));
        pm[qs] = p;
      }
      bool need = (pm[0] > m_[0]) | (pm[1] > m_[1]);
      if (__any((int)need)) {
        float es[2];
#pragma unroll
        for (int qs = 0; qs < 2; ++qs) {
          float nm = fmaxf(m_[qs], pm[qs]);
          es[qs] = ex2(m_[qs] - nm);
          m_[qs] = nm;
          l_[qs] *= es[qs];
        }
#pragma unroll
        for (int r = 0; r < 4; ++r) {
          float e0 = __shfl(es[0], l4 * 4 + r);
          float e1 = __shfl(es[1], l4 * 4 + r);
#pragma unroll
          for (int dt = 0; dt < 4; ++dt) {
            o_[0][dt][r] *= e0;
            o_[1][dt][r] *= e1;
          }
        }
      }
#pragma unroll
      for (int qs = 0; qs < 2; ++qs) {
#pragma unroll
        for (int nt = 0; nt < 2; ++nt)
#pragma unroll
          for (int r = 0; r < 4; ++r)
            s[qs][nt][r] = ex2(s[qs][nt][r] - m_[qs]);
        l_[qs] += ((s[qs][0][0] + s[qs][0][1]) + (s[qs][0][2] + s[qs][0][3]))
                + ((s[qs][1][0] + s[qs][1][1]) + (s[qs][1][2] + s[qs][1][3]));
      }
    }

    // ---- pack P into A-fragment directly (k-slot pi: in-lane!) ----
    bf16x8 pa[2];
#pragma unroll
    for (int qs = 0; qs < 2; ++qs) {
      u32 w0 = (u32)f2bf(s[qs][0][0]) | ((u32)f2bf(s[qs][0][1]) << 16);
      u32 w1 = (u32)f2bf(s[qs][0][2]) | ((u32)f2bf(s[qs][0][3]) << 16);
      u32 w2 = (u32)f2bf(s[qs][1][0]) | ((u32)f2bf(s[qs][1][1]) << 16);
      u32 w3 = (u32)f2bf(s[qs][1][2]) | ((u32)f2bf(s[qs][1][3]) << 16);
      pa[qs] = __builtin_bit_cast(bf16x8, u32x4{w0, w1, w2, w3});
    }

    // ---- O += P V (V B-op reads matching pi granules) ----
    const int gc0 = kvh * 4 + (l4 >> 1);
    const int hb = (l4 & 1) * 8;
    const int sx = l15 & 7;
#pragma unroll
    for (int dt = 0; dt < 4; ++dt) {
      int d = dt * 16 + l15;
      const char* rowp = Vc + d * 128 + hb;
      u32x2 vlo = *(const u32x2*)(rowp + ((gc0 ^ sx) << 4));
      u32x2 vhi = *(const u32x2*)(rowp + (((gc0 + 2) ^ sx) << 4));
      bf16x8 vf = __builtin_bit_cast(bf16x8, u32x4{vlo[0], vlo[1], vhi[0], vhi[1]});
      o_[0][dt] = __builtin_amdgcn_mfma_f32_16x16x32_bf16(pa[0], vf, o_[0][dt], 0, 0, 0);
      o_[1][dt] = __builtin_amdgcn_mfma_f32_16x16x32_bf16(pa[1], vf, o_[1][dt], 0, 0, 0);
    }
  }

  // ---- finish per-wave l across l4 ----
  float lt0 = l_[0] + __shfl_xor(l_[0], 16); lt0 += __shfl_xor(lt0, 32);
  float lt1 = l_[1] + __shfl_xor(l_[1], 16); lt1 += __shfl_xor(lt1, 32);

  // ---- in-block 2-way merge via LDS (K/V buffers are dead now) ----
  __syncthreads();
  u16* pw = (u16*)SM + wid * 2048;               // 32q x 64d bf16 per wave
#pragma unroll
  for (int qs = 0; qs < 2; ++qs)
#pragma unroll
    for (int dt = 0; dt < 4; ++dt)
#pragma unroll
      for (int r = 0; r < 4; ++r)
        pw[(qs * 16 + l4 * 4 + r) * 64 + dt * 16 + l15] = f2bf(o_[qs][dt][r]);
  if (l4 == 0) {
    MLsh[wid][l15]      = m_[0];  MLsh[wid][32 + l15] = lt0;
    MLsh[wid][16 + l15] = m_[1];  MLsh[wid][48 + l15] = lt1;
  }
  __syncthreads();

  // wave wid finalizes rows q = wid*16 + l4*4 + r (q-half = wid>>1)
  const int wA = (wid >> 1) << 1, wB = wA + 1;
  const u16* pA = (const u16*)SM + wA * 2048;
  const u16* pB = (const u16*)SM + wB * 2048;
  float wtA[4], wtB[4], inv[4], Mx[4], Lx[4];
  int qlr[4];
#pragma unroll
  for (int r = 0; r < 4; ++r) {
    int ql = (wid & 1) * 16 + l4 * 4 + r;
    qlr[r] = ql;
    float mA = MLsh[wA][ql], lA = MLsh[wA][32 + ql];
    float mB = MLsh[wB][ql], lB = MLsh[wB][32 + ql];
    float M2 = fmaxf(mA, mB);
    float a = ex2(mA - M2), bb2 = ex2(mB - M2);
    float L = lA * a + lB * bb2;
    Mx[r] = M2; Lx[r] = L;
    wtA[r] = a; wtB[r] = bb2;
    inv[r] = 1.0f / L;
  }

  if (mode == 2) {
#pragma unroll
    for (int dt = 0; dt < 4; ++dt)
#pragma unroll
      for (int r = 0; r < 4; ++r) {
        int idx2 = qlr[r] * 64 + dt * 16 + l15;
        float val = (bf2f(pA[idx2]) * wtA[r] + bf2f(pB[idx2]) * wtB[r]) * inv[r];
        int tok = qt * 64 + wid * 16 + l4 * 4 + r;
        O[(((size_t)(b * S_LEN + tok)) << 10) + h * 64 + dt * 16 + l15] = f2bf(val);
      }
  } else {
    const int pslot = (((bh << 4) + (qt - 16)) << 1) + mode;
    u16* pb = pO + ((size_t)pslot << 12);
#pragma unroll
    for (int dt = 0; dt < 4; ++dt)
#pragma unroll
      for (int r = 0; r < 4; ++r) {
        int idx2 = qlr[r] * 64 + dt * 16 + l15;
        float val = (bf2f(pA[idx2]) * wtA[r] + bf2f(pB[idx2]) * wtB[r]) * inv[r];
        int row = wid * 16 + l4 * 4 + r;
        pb[row * 64 + dt * 16 + l15] = f2bf(val);
      }
    if (l15 == 0) {
#pragma unroll
      for (int r = 0; r < 4; ++r) {
        int row = wid * 16 + l4 * 4 + r;
        ML[pslot * 128 + row] = Mx[r];
        ML[pslot * 128 + 64 + row] = Lx[r];
      }
    }
  }
}

// ---------------------------------------------------------------------------
// Merge the two partials of each qt>=16 q-tile into O. (unchanged)
// ---------------------------------------------------------------------------
__global__ __launch_bounds__(256) void combine(
    const u16* __restrict__ pO, const float* __restrict__ ML,
    u16* __restrict__ O) {
  const int qi = blockIdx.x, bh = blockIdx.y;
  const int b = bh >> 4, h = bh & 15;
  const int t = threadIdx.x;
  const int row = t >> 2, cblk = (t & 3) << 4;      // 16 cols per thread
  const int s0 = (((bh << 4) + qi) << 1), s1 = s0 + 1;
  float m0 = ML[s0 * 128 + row], l0 = ML[s0 * 128 + 64 + row];
  float m1 = ML[s1 * 128 + row], l1 = ML[s1 * 128 + 64 + row];
  float m = fmaxf(m0, m1);
  float w0 = l0 * ex2(m0 - m), w1 = l1 * ex2(m1 - m);
  float inv = 1.0f / (w0 + w1);
  w0 *= inv; w1 *= inv;
  const u16* p0 = pO + (((size_t)s0) << 12) + row * 64 + cblk;
  const u16* p1 = pO + (((size_t)s1) << 12) + row * 64 + cblk;
  const int tok = (16 + qi) * 64 + row;
  u16* dst = O + (((size_t)(b * S_LEN + tok)) << 10) + h * 64 + cblk;
#pragma unroll
  for (int half = 0; half < 2; ++half) {
    u16x8 a = *(const u16x8*)(p0 + half * 8);
    u16x8 c = *(const u16x8*)(p1 + half * 8);
    u16x8 o;
#pragma unroll
    for (int j = 0; j < 8; ++j)
      o[j] = f2bf(w0 * bf2f(a[j]) + w1 * bf2f(c[j]));
    *(u16x8*)(dst + half * 8) = o;
  }
}

// ---------------------------------------------------------------------------
extern "C" void kernel_launch(void* const* d_in, const int* in_sizes, int n_in,
                              void* d_out, int out_size, void* d_ws, size_t ws_size,
                              hipStream_t stream) {
  const float* x    = (const float*)d_in[0];
  const float* Wqkv = (const float*)d_in[1];
  const float* bqkv = (const float*)d_in[2];
  const float* Wout = (const float*)d_in[3];
  const float* bout = (const float*)d_in[4];
  float* out = (float*)d_out;

  // workspace layout (u16 elems): ~51 MiB total
  u16* xb    = (u16*)d_ws;            // 4,194,304   (dead after QKV GEMM)
  u16* wqkvb = xb + 4194304;          // 3,145,728   (dead after QKV GEMM)
  u16* woutb = wqkvb + 3145728;       // 1,048,576
  u16* qkb   = woutb + 1048576;       // 8,388,608  (Q|K, [4096][2048])
  u16* vtb   = qkb + 8388608;         // 4,194,304  (V^T, [32][64][2048])
  u16* ob    = vtb + 4194304;         // 4,194,304
  // attention partials alias the dead xb/wqkvb regions:
  u16*   pO = xb;                     // 1024 slots x 64x64 bf16 = 4,194,304 u16
  float* ML = (float*)wqkvb;          // 1024 slots x 128 f32    = 131,072 f32

  f2bf_all<<<2048, 256, 0, stream>>>(x, Wqkv, Wout, xb, wqkvb, woutb);

  gemm_bt<2><<<dim3(24, 32), 256, 0, stream>>>(xb, wqkvb, bqkv, qkb, vtb,
                                               4096, 3072, 1024, 0);
  attn11<<<dim3(1536), 256, 0, stream>>>(qkb, vtb, ob, pO, ML);
  combine<<<dim3(16, 32), 256, 0, stream>>>(pO, ML, ob);
  gemm_bt<0><<<dim3(8, 32), 256, 0, stream>>>(ob, woutb, bout, out, nullptr,
                                              4096, 1024, 1024, 1024);
}